// Round 1
// baseline (539.224 us; speedup 1.0000x reference)
//
#include <hip/hip_runtime.h>
#include <hip/hip_bf16.h>
#include <math.h>

#define N_NODES 50000
#define N_EDGES 800000
#define F_IN    11
#define HID     128
#define NC      16
#define NG      64
#define E_TOT   (N_EDGES + N_NODES)   // 850000 edges incl. self-loops
#define NBLK_POOL ((N_NODES + 255) / 256)  // 196
#define NEG_SLOPE 0.2f

__device__ __forceinline__ float leaky(float x) { return x >= 0.f ? x : NEG_SLOPE * x; }

// ---------------- CSR build (dst-sorted) ----------------

__global__ void zero_deg_kernel(int* __restrict__ deg) {
    int i = blockIdx.x * blockDim.x + threadIdx.x;
    if (i < N_NODES) deg[i] = 0;
}

__global__ void hist_kernel(const int* __restrict__ ei, int* __restrict__ deg) {
    int id = blockIdx.x * blockDim.x + threadIdx.x;
    int stride = gridDim.x * blockDim.x;
    for (; id < E_TOT; id += stride) {
        int d = (id < N_EDGES) ? ei[N_EDGES + id] : (id - N_EDGES);  // dst row, or self-loop
        atomicAdd(&deg[d], 1);
    }
}

// block 256 threads, 4 elems/thread -> 1024 elems/block; 49 blocks cover N
__global__ void scan1_kernel(const int* __restrict__ deg, int* __restrict__ off,
                             int* __restrict__ bsum) {
    __shared__ int ls[256];
    int tid = threadIdx.x;
    int base = blockIdx.x * 1024 + tid * 4;
    int v0 = (base + 0 < N_NODES) ? deg[base + 0] : 0;
    int v1 = (base + 1 < N_NODES) ? deg[base + 1] : 0;
    int v2 = (base + 2 < N_NODES) ? deg[base + 2] : 0;
    int v3 = (base + 3 < N_NODES) ? deg[base + 3] : 0;
    int pre1 = v0, pre2 = v0 + v1, pre3 = v0 + v1 + v2;
    int tot = pre3 + v3;
    ls[tid] = tot;
    __syncthreads();
    for (int ofs = 1; ofs < 256; ofs <<= 1) {
        int x = (tid >= ofs) ? ls[tid - ofs] : 0;
        __syncthreads();
        ls[tid] += x;
        __syncthreads();
    }
    int excl = (tid > 0) ? ls[tid - 1] : 0;
    if (base + 0 < N_NODES) off[base + 0] = excl;
    if (base + 1 < N_NODES) off[base + 1] = excl + pre1;
    if (base + 2 < N_NODES) off[base + 2] = excl + pre2;
    if (base + 3 < N_NODES) off[base + 3] = excl + pre3;
    if (tid == 255) bsum[blockIdx.x] = ls[255];
}

__global__ void scan2_kernel(int* __restrict__ bsum, int nblk) {
    __shared__ int ls[256];
    int tid = threadIdx.x;
    ls[tid] = (tid < nblk) ? bsum[tid] : 0;
    __syncthreads();
    for (int ofs = 1; ofs < 256; ofs <<= 1) {
        int x = (tid >= ofs) ? ls[tid - ofs] : 0;
        __syncthreads();
        ls[tid] += x;
        __syncthreads();
    }
    bsum[tid] = (tid > 0) ? ls[tid - 1] : 0;  // exclusive
}

__global__ void scan3_kernel(int* __restrict__ off, const int* __restrict__ bsum,
                             int* __restrict__ pos) {
    int i = blockIdx.x * blockDim.x + threadIdx.x;
    if (i < N_NODES) {
        int o = off[i] + bsum[i >> 10];
        off[i] = o;
        pos[i] = o;
    }
    if (i == 0) off[N_NODES] = E_TOT;
}

__global__ void scatter_kernel(const int* __restrict__ ei, int* __restrict__ pos,
                               int* __restrict__ csr) {
    int id = blockIdx.x * blockDim.x + threadIdx.x;
    int stride = gridDim.x * blockDim.x;
    for (; id < E_TOT; id += stride) {
        int s, d;
        if (id < N_EDGES) { s = ei[id]; d = ei[N_EDGES + id]; }
        else { s = id - N_EDGES; d = s; }
        int slot = atomicAdd(&pos[d], 1);
        csr[slot] = s;
    }
}

// ---------------- GEMMs (f32 VALU; no fp32 MFMA on CDNA4) ----------------

// x[N,11] @ W[11,128] -> h[N,128]; one row per block of 128 threads
__global__ void gemm1_kernel(const float* __restrict__ x, const float* __restrict__ W,
                             float* __restrict__ h) {
    __shared__ float xr[F_IN];
    int row = blockIdx.x;
    int t = threadIdx.x;
    if (t < F_IN) xr[t] = x[row * F_IN + t];
    __syncthreads();
    float acc = 0.f;
#pragma unroll
    for (int k = 0; k < F_IN; ++k) acc = fmaf(xr[k], W[k * HID + t], acc);
    h[(size_t)row * HID + t] = acc;
}

// A[N,128] @ W[128,128] -> out[N,128]; block 256, 16 rows/block, 8 rows/thread-regtile
__global__ __launch_bounds__(256) void gemm2_kernel(const float* __restrict__ A,
                                                    const float* __restrict__ W,
                                                    float* __restrict__ outp) {
    __shared__ float hs[16][HID];   // reads are wave-uniform broadcasts -> no conflicts
    int tid = threadIdx.x;
    int row0 = blockIdx.x * 16;
    for (int i = tid; i < 16 * HID; i += 256) {
        int r = i >> 7, c = i & 127;
        int gr = row0 + r;
        hs[r][c] = (gr < N_NODES) ? A[(size_t)gr * HID + c] : 0.f;
    }
    __syncthreads();
    int col = tid & 127, rg = tid >> 7;
    float acc[8] = {0.f, 0.f, 0.f, 0.f, 0.f, 0.f, 0.f, 0.f};
    for (int k4 = 0; k4 < HID / 4; ++k4) {
        float4 hv[8];
#pragma unroll
        for (int r = 0; r < 8; ++r)
            hv[r] = *(const float4*)&hs[rg * 8 + r][k4 * 4];
#pragma unroll
        for (int kk = 0; kk < 4; ++kk) {
            float w = W[(k4 * 4 + kk) * HID + col];
#pragma unroll
            for (int r = 0; r < 8; ++r)
                acc[r] = fmaf(((const float*)&hv[r])[kk], w, acc[r]);
        }
    }
#pragma unroll
    for (int r = 0; r < 8; ++r) {
        int gr = row0 + rg * 8 + r;
        if (gr < N_NODES) outp[(size_t)gr * HID + col] = acc[r];
    }
}

// A[N,128] @ W[128,16] -> out[N,16]; block 256 = 16 rows x 16 cols
__global__ __launch_bounds__(256) void gemm3_kernel(const float* __restrict__ A,
                                                    const float* __restrict__ W,
                                                    float* __restrict__ outp) {
    __shared__ float hs[16][HID + 1];  // pad: 16 distinct rows read per k
    int tid = threadIdx.x;
    int row0 = blockIdx.x * 16;
    for (int i = tid; i < 16 * HID; i += 256) {
        int r = i >> 7, c = i & 127;
        int gr = row0 + r;
        hs[r][c] = (gr < N_NODES) ? A[(size_t)gr * HID + c] : 0.f;
    }
    __syncthreads();
    int col = tid & 15, r = tid >> 4;
    float acc = 0.f;
#pragma unroll 4
    for (int k = 0; k < HID; ++k) acc = fmaf(hs[r][k], W[k * NC + col], acc);
    int gr = row0 + r;
    if (gr < N_NODES) outp[(size_t)gr * NC + col] = acc;
}

// ---------------- attention logits: asv[n] = h[n,:]·a_src, adv[n] = h[n,:]·a_dst ----------------

template <int C>
__global__ void alpha_kernel(const float* __restrict__ h, const float* __restrict__ a_s,
                             const float* __restrict__ a_d, float* __restrict__ asv,
                             float* __restrict__ adv) {
    int lane = threadIdx.x & 63;
    int n = (blockIdx.x * blockDim.x + threadIdx.x) >> 6;
    if (n >= N_NODES) return;
    float ps = 0.f, pd = 0.f;
#pragma unroll
    for (int c = lane; c < C; c += 64) {
        float v = h[(size_t)n * C + c];
        ps = fmaf(v, a_s[c], ps);
        pd = fmaf(v, a_d[c], pd);
    }
#pragma unroll
    for (int k = 32; k; k >>= 1) {
        ps += __shfl_xor(ps, k);
        pd += __shfl_xor(pd, k);
    }
    if (lane == 0) { asv[n] = ps; adv[n] = pd; }
}

// ---------------- fused segment-softmax + weighted aggregation ----------------
// One wave per dst node. Phase 1: edges lane-parallel (online max / exp / denom).
// Phase 2: channels lane-parallel (float2/lane), serial over edges via shfl broadcast.

template <int C>
__global__ __launch_bounds__(256) void agg_kernel(
    const float* __restrict__ h, const int* __restrict__ off, const int* __restrict__ csr,
    const float* __restrict__ asv, const float* __restrict__ adv,
    const float* __restrict__ bias, float* __restrict__ outp) {
    constexpr int PAIRS = C / 2;  // channels per lane pair: 64 (C=128) or 8 (C=16)
    int lane = threadIdx.x & 63;
    int n = (blockIdx.x * blockDim.x + threadIdx.x) >> 6;
    if (n >= N_NODES) return;
    int o0 = off[n], o1 = off[n + 1];
    float ad_n = adv[n];
    float m = -INFINITY, den = 0.f;
    float ax = 0.f, ay = 0.f;
    for (int base = o0; base < o1; base += 64) {
        int j = base + lane;
        bool valid = j < o1;
        int s = valid ? csr[j] : 0;
        float e = valid ? leaky(asv[s] + ad_n) : -INFINITY;
        float cm = e;
#pragma unroll
        for (int k = 32; k; k >>= 1) cm = fmaxf(cm, __shfl_xor(cm, k));
        float nm = fmaxf(m, cm);
        float rs = __expf(m - nm);  // m==-inf first iter -> 0, acc already 0
        ax *= rs; ay *= rs; den *= rs;
        float w = valid ? __expf(e - nm) : 0.f;
        float ws = w;
#pragma unroll
        for (int k = 32; k; k >>= 1) ws += __shfl_xor(ws, k);
        den += ws;
        int cnt = min(64, o1 - base);
        for (int t = 0; t < cnt; ++t) {
            float wt = __shfl(w, t);
            int st = __shfl(s, t);
            if (lane < PAIRS) {
                float2 hv = *(const float2*)(h + (size_t)st * C + lane * 2);
                ax = fmaf(wt, hv.x, ax);
                ay = fmaf(wt, hv.y, ay);
            }
        }
        m = nm;
    }
    if (lane < PAIRS) {
        float inv = 1.f / den;  // deg >= 1 always (self-loop)
        float vx = ax * inv + bias[lane * 2];
        float vy = ay * inv + bias[lane * 2 + 1];
        outp[(size_t)n * C + lane * 2]     = fmaxf(vx, 0.f);
        outp[(size_t)n * C + lane * 2 + 1] = fmaxf(vy, 0.f);
    }
}

// ---------------- global mean pool + sigmoid ----------------

__global__ void pool_partial_kernel(const float* __restrict__ h3, const int* __restrict__ batch,
                                    float* __restrict__ part) {
    __shared__ float sp[NG * 17];
    int tid = threadIdx.x;
    for (int i = tid; i < NG * 17; i += 256) sp[i] = 0.f;
    __syncthreads();
    int n = blockIdx.x * 256 + tid;
    if (n < N_NODES) {
        int g = batch[n];
        const float4* hv = (const float4*)(h3 + (size_t)n * NC);
#pragma unroll
        for (int j = 0; j < 4; ++j) {
            float4 v = hv[j];
            atomicAdd(&sp[g * 17 + j * 4 + 0], v.x);
            atomicAdd(&sp[g * 17 + j * 4 + 1], v.y);
            atomicAdd(&sp[g * 17 + j * 4 + 2], v.z);
            atomicAdd(&sp[g * 17 + j * 4 + 3], v.w);
        }
        atomicAdd(&sp[g * 17 + 16], 1.f);
    }
    __syncthreads();
    for (int i = tid; i < NG * 17; i += 256) part[(size_t)blockIdx.x * (NG * 17) + i] = sp[i];
}

__global__ void pool_final_kernel(const float* __restrict__ part, float* __restrict__ outp) {
    int tid = threadIdx.x;  // 1024 = 64 graphs x 16 classes
    int g = tid >> 4, c = tid & 15;
    float sum = 0.f, cnt = 0.f;
    for (int b = 0; b < NBLK_POOL; ++b) {
        sum += part[(size_t)b * (NG * 17) + g * 17 + c];
        cnt += part[(size_t)b * (NG * 17) + g * 17 + 16];
    }
    float v = sum / fmaxf(cnt, 1.f);
    outp[g * NC + c] = 1.f / (1.f + __expf(-v));
}

// ---------------- launch ----------------

extern "C" void kernel_launch(void* const* d_in, const int* in_sizes, int n_in,
                              void* d_out, int out_size, void* d_ws, size_t ws_size,
                              hipStream_t stream) {
    const float* x   = (const float*)d_in[0];
    const int*   ei  = (const int*)d_in[1];
    // d_in[2] edge_attr: unused by reference
    const int*   bat = (const int*)d_in[3];
    const float* W1  = (const float*)d_in[4];
    const float* as1 = (const float*)d_in[5];
    const float* ad1 = (const float*)d_in[6];
    const float* b1  = (const float*)d_in[7];
    const float* W2  = (const float*)d_in[8];
    const float* as2 = (const float*)d_in[9];
    const float* ad2 = (const float*)d_in[10];
    const float* b2  = (const float*)d_in[11];
    const float* W3  = (const float*)d_in[12];
    const float* as3 = (const float*)d_in[13];
    const float* ad3 = (const float*)d_in[14];
    const float* b3  = (const float*)d_in[15];
    float* outp = (float*)d_out;

    char* p = (char*)d_ws;
    auto carve = [&](size_t bytes) {
        char* r = p;
        p += (bytes + 255) & ~(size_t)255;
        return r;
    };
    int*   deg  = (int*)carve((size_t)N_NODES * 4);
    int*   off  = (int*)carve((size_t)(N_NODES + 1) * 4);
    int*   pos  = (int*)carve((size_t)N_NODES * 4);
    int*   csr  = (int*)carve((size_t)E_TOT * 4);
    int*   bsum = (int*)carve(256 * 4);
    float* hA   = (float*)carve((size_t)N_NODES * HID * 4);
    float* hB   = (float*)carve((size_t)N_NODES * HID * 4);
    float* asv  = (float*)carve((size_t)N_NODES * 4);
    float* adv  = (float*)carve((size_t)N_NODES * 4);
    float* part = (float*)carve((size_t)NBLK_POOL * NG * 17 * 4);

    const int scan_blocks = (N_NODES + 1023) / 1024;  // 49

    // CSR build
    zero_deg_kernel<<<(N_NODES + 255) / 256, 256, 0, stream>>>(deg);
    hist_kernel<<<2048, 256, 0, stream>>>(ei, deg);
    scan1_kernel<<<scan_blocks, 256, 0, stream>>>(deg, off, bsum);
    scan2_kernel<<<1, 256, 0, stream>>>(bsum, scan_blocks);
    scan3_kernel<<<(N_NODES + 255) / 256, 256, 0, stream>>>(off, bsum, pos);
    scatter_kernel<<<2048, 256, 0, stream>>>(ei, pos, csr);

    // Layer 1: 11 -> 128
    gemm1_kernel<<<N_NODES, 128, 0, stream>>>(x, W1, hA);
    alpha_kernel<HID><<<(N_NODES + 3) / 4, 256, 0, stream>>>(hA, as1, ad1, asv, adv);
    agg_kernel<HID><<<(N_NODES + 3) / 4, 256, 0, stream>>>(hA, off, csr, asv, adv, b1, hB);

    // Layer 2: 128 -> 128
    gemm2_kernel<<<(N_NODES + 15) / 16, 256, 0, stream>>>(hB, W2, hA);
    alpha_kernel<HID><<<(N_NODES + 3) / 4, 256, 0, stream>>>(hA, as2, ad2, asv, adv);
    agg_kernel<HID><<<(N_NODES + 3) / 4, 256, 0, stream>>>(hA, off, csr, asv, adv, b2, hB);

    // Layer 3: 128 -> 16
    gemm3_kernel<<<(N_NODES + 15) / 16, 256, 0, stream>>>(hB, W3, hA);  // hA reused as [N,16]
    alpha_kernel<NC><<<(N_NODES + 3) / 4, 256, 0, stream>>>(hA, as3, ad3, asv, adv);
    agg_kernel<NC><<<(N_NODES + 3) / 4, 256, 0, stream>>>(hA, off, csr, asv, adv, b3, hB);

    // Pool + sigmoid
    pool_partial_kernel<<<NBLK_POOL, 256, 0, stream>>>(hB, bat, part);
    pool_final_kernel<<<1, 1024, 0, stream>>>(part, outp);
}

// Round 3
// 493.302 us; speedup vs baseline: 1.0931x; 1.0931x over previous
//
#include <hip/hip_runtime.h>
#include <hip/hip_bf16.h>
#include <math.h>

#define N_NODES 50000
#define N_EDGES 800000
#define F_IN    11
#define HID     128
#define NC      16
#define NG      64
#define E_TOT   (N_EDGES + N_NODES)   // 850000 edges incl. self-loops
#define NBLK_POOL ((N_NODES + 255) / 256)  // 196
#define NEG_SLOPE 0.2f

__device__ __forceinline__ float leaky(float x) { return x >= 0.f ? x : NEG_SLOPE * x; }

// ---------------- CSR build (dst-sorted) ----------------

__global__ void zero_deg_kernel(int* __restrict__ deg) {
    int i = blockIdx.x * blockDim.x + threadIdx.x;
    if (i < N_NODES) deg[i] = 0;
}

__global__ void hist_kernel(const int* __restrict__ ei, int* __restrict__ deg) {
    int id = blockIdx.x * blockDim.x + threadIdx.x;
    int stride = gridDim.x * blockDim.x;
    for (; id < E_TOT; id += stride) {
        int d = (id < N_EDGES) ? ei[N_EDGES + id] : (id - N_EDGES);  // dst row, or self-loop
        atomicAdd(&deg[d], 1);
    }
}

// block 256 threads, 4 elems/thread -> 1024 elems/block; 49 blocks cover N
__global__ void scan1_kernel(const int* __restrict__ deg, int* __restrict__ off,
                             int* __restrict__ bsum) {
    __shared__ int ls[256];
    int tid = threadIdx.x;
    int base = blockIdx.x * 1024 + tid * 4;
    int v0 = (base + 0 < N_NODES) ? deg[base + 0] : 0;
    int v1 = (base + 1 < N_NODES) ? deg[base + 1] : 0;
    int v2 = (base + 2 < N_NODES) ? deg[base + 2] : 0;
    int v3 = (base + 3 < N_NODES) ? deg[base + 3] : 0;
    int pre1 = v0, pre2 = v0 + v1, pre3 = v0 + v1 + v2;
    int tot = pre3 + v3;
    ls[tid] = tot;
    __syncthreads();
    for (int ofs = 1; ofs < 256; ofs <<= 1) {
        int x = (tid >= ofs) ? ls[tid - ofs] : 0;
        __syncthreads();
        ls[tid] += x;
        __syncthreads();
    }
    int excl = (tid > 0) ? ls[tid - 1] : 0;
    if (base + 0 < N_NODES) off[base + 0] = excl;
    if (base + 1 < N_NODES) off[base + 1] = excl + pre1;
    if (base + 2 < N_NODES) off[base + 2] = excl + pre2;
    if (base + 3 < N_NODES) off[base + 3] = excl + pre3;
    if (tid == 255) bsum[blockIdx.x] = ls[255];
}

__global__ void scan2_kernel(int* __restrict__ bsum, int nblk) {
    __shared__ int ls[256];
    int tid = threadIdx.x;
    ls[tid] = (tid < nblk) ? bsum[tid] : 0;
    __syncthreads();
    for (int ofs = 1; ofs < 256; ofs <<= 1) {
        int x = (tid >= ofs) ? ls[tid - ofs] : 0;
        __syncthreads();
        ls[tid] += x;
        __syncthreads();
    }
    bsum[tid] = (tid > 0) ? ls[tid - 1] : 0;  // exclusive
}

__global__ void scan3_kernel(int* __restrict__ off, const int* __restrict__ bsum,
                             int* __restrict__ pos) {
    int i = blockIdx.x * blockDim.x + threadIdx.x;
    if (i < N_NODES) {
        int o = off[i] + bsum[i >> 10];
        off[i] = o;
        pos[i] = o;
    }
    if (i == 0) off[N_NODES] = E_TOT;
}

__global__ void scatter_kernel(const int* __restrict__ ei, int* __restrict__ pos,
                               int* __restrict__ csr) {
    int id = blockIdx.x * blockDim.x + threadIdx.x;
    int stride = gridDim.x * blockDim.x;
    for (; id < E_TOT; id += stride) {
        int s, d;
        if (id < N_EDGES) { s = ei[id]; d = ei[N_EDGES + id]; }
        else { s = id - N_EDGES; d = s; }
        int slot = atomicAdd(&pos[d], 1);
        csr[slot] = s;
    }
}

// ---------------- GEMMs (f32 VALU; no fp32 MFMA on CDNA4) ----------------

// x[N,11] @ W[11,128] -> h[N,128]; one row per block of 128 threads
__global__ void gemm1_kernel(const float* __restrict__ x, const float* __restrict__ W,
                             float* __restrict__ h) {
    __shared__ float xr[F_IN];
    int row = blockIdx.x;
    int t = threadIdx.x;
    if (t < F_IN) xr[t] = x[row * F_IN + t];
    __syncthreads();
    float acc = 0.f;
#pragma unroll
    for (int k = 0; k < F_IN; ++k) acc = fmaf(xr[k], W[k * HID + t], acc);
    h[(size_t)row * HID + t] = acc;
}

// A[N,128] @ W[128,128] -> out[N,128]; block 256, 16 rows/block, 8 rows/thread-regtile
__global__ __launch_bounds__(256) void gemm2_kernel(const float* __restrict__ A,
                                                    const float* __restrict__ W,
                                                    float* __restrict__ outp) {
    __shared__ float hs[16][HID];   // reads are wave-uniform broadcasts -> no conflicts
    int tid = threadIdx.x;
    int row0 = blockIdx.x * 16;
    for (int i = tid; i < 16 * HID; i += 256) {
        int r = i >> 7, c = i & 127;
        int gr = row0 + r;
        hs[r][c] = (gr < N_NODES) ? A[(size_t)gr * HID + c] : 0.f;
    }
    __syncthreads();
    int col = tid & 127, rg = tid >> 7;
    float acc[8] = {0.f, 0.f, 0.f, 0.f, 0.f, 0.f, 0.f, 0.f};
    for (int k4 = 0; k4 < HID / 4; ++k4) {
        float4 hv[8];
#pragma unroll
        for (int r = 0; r < 8; ++r)
            hv[r] = *(const float4*)&hs[rg * 8 + r][k4 * 4];
#pragma unroll
        for (int kk = 0; kk < 4; ++kk) {
            float w = W[(k4 * 4 + kk) * HID + col];
#pragma unroll
            for (int r = 0; r < 8; ++r)
                acc[r] = fmaf(((const float*)&hv[r])[kk], w, acc[r]);
        }
    }
#pragma unroll
    for (int r = 0; r < 8; ++r) {
        int gr = row0 + rg * 8 + r;
        if (gr < N_NODES) outp[(size_t)gr * HID + col] = acc[r];
    }
}

// A[N,128] @ W[128,16] -> out[N,16]; block 256 = 16 rows x 16 cols
__global__ __launch_bounds__(256) void gemm3_kernel(const float* __restrict__ A,
                                                    const float* __restrict__ W,
                                                    float* __restrict__ outp) {
    __shared__ float hs[16][HID + 1];  // pad: 16 distinct rows read per k
    int tid = threadIdx.x;
    int row0 = blockIdx.x * 16;
    for (int i = tid; i < 16 * HID; i += 256) {
        int r = i >> 7, c = i & 127;
        int gr = row0 + r;
        hs[r][c] = (gr < N_NODES) ? A[(size_t)gr * HID + c] : 0.f;
    }
    __syncthreads();
    int col = tid & 15, r = tid >> 4;
    float acc = 0.f;
#pragma unroll 4
    for (int k = 0; k < HID; ++k) acc = fmaf(hs[r][k], W[k * NC + col], acc);
    int gr = row0 + r;
    if (gr < N_NODES) outp[(size_t)gr * NC + col] = acc;
}

// ---------------- attention logits: asv[n] = h[n,:]·a_src, adv[n] = h[n,:]·a_dst ----------------

template <int C>
__global__ void alpha_kernel(const float* __restrict__ h, const float* __restrict__ a_s,
                             const float* __restrict__ a_d, float* __restrict__ asv,
                             float* __restrict__ adv) {
    int lane = threadIdx.x & 63;
    int n = (blockIdx.x * blockDim.x + threadIdx.x) >> 6;
    if (n >= N_NODES) return;
    float ps = 0.f, pd = 0.f;
#pragma unroll
    for (int c = lane; c < C; c += 64) {
        float v = h[(size_t)n * C + c];
        ps = fmaf(v, a_s[c], ps);
        pd = fmaf(v, a_d[c], pd);
    }
#pragma unroll
    for (int k = 32; k; k >>= 1) {
        ps += __shfl_xor(ps, k);
        pd += __shfl_xor(pd, k);
    }
    if (lane == 0) { asv[n] = ps; adv[n] = pd; }
}

// ---------------- fused segment-softmax + weighted aggregation ----------------
// One wave per dst node. Phase 1 (per 64-edge batch): edges lane-parallel
// (online max / exp / denom via shfl reductions). Phase 2: half-wave per edge
// (32 lanes x float4 = 512B row), 4 edges unrolled -> 4 loads in flight/lane.

__global__ __launch_bounds__(256) void agg128_kernel(
    const float* __restrict__ h, const int* __restrict__ off, const int* __restrict__ csr,
    const float* __restrict__ asv, const float* __restrict__ adv,
    const float* __restrict__ bias, float* __restrict__ outp) {
    int lane = threadIdx.x & 63;
    int n = (blockIdx.x * blockDim.x + threadIdx.x) >> 6;
    if (n >= N_NODES) return;
    int o0 = off[n], o1 = off[n + 1];
    float ad_n = adv[n];
    int half = lane >> 5;        // which edge of a pair this half-wave handles
    int qc = lane & 31;          // float4 index within the 128-ch row
    const float4* hp = (const float4*)h;
    float m = -INFINITY, den = 0.f;
    float4 acc = make_float4(0.f, 0.f, 0.f, 0.f);
    for (int base = o0; base < o1; base += 64) {
        int j = base + lane;
        bool valid = j < o1;
        int s = valid ? csr[j] : 0;
        float e = valid ? leaky(asv[s] + ad_n) : -INFINITY;
        float cm = e;
#pragma unroll
        for (int k = 32; k; k >>= 1) cm = fmaxf(cm, __shfl_xor(cm, k));
        float nm = fmaxf(m, cm);
        float rs = __expf(m - nm);  // m==-inf first batch -> 0, acc already 0
        den *= rs; acc.x *= rs; acc.y *= rs; acc.z *= rs; acc.w *= rs;
        float w = valid ? __expf(e - nm) : 0.f;
        float ws = w;
#pragma unroll
        for (int k = 32; k; k >>= 1) ws += __shfl_xor(ws, k);
        den += ws;
        m = nm;
        int cnt = min(64, o1 - base);
        int t = 0;
        for (; t + 8 <= cnt; t += 8) {  // 8 edges per iter: 4 rows in flight per lane
            int e0 = t + half, e1 = t + 2 + half, e2 = t + 4 + half, e3 = t + 6 + half;
            int s0 = __shfl(s, e0), s1 = __shfl(s, e1), s2 = __shfl(s, e2), s3 = __shfl(s, e3);
            float w0 = __shfl(w, e0), w1 = __shfl(w, e1), w2 = __shfl(w, e2), w3 = __shfl(w, e3);
            float4 v0 = hp[(size_t)s0 * 32 + qc];
            float4 v1 = hp[(size_t)s1 * 32 + qc];
            float4 v2 = hp[(size_t)s2 * 32 + qc];
            float4 v3 = hp[(size_t)s3 * 32 + qc];
            acc.x = fmaf(w0, v0.x, acc.x); acc.y = fmaf(w0, v0.y, acc.y);
            acc.z = fmaf(w0, v0.z, acc.z); acc.w = fmaf(w0, v0.w, acc.w);
            acc.x = fmaf(w1, v1.x, acc.x); acc.y = fmaf(w1, v1.y, acc.y);
            acc.z = fmaf(w1, v1.z, acc.z); acc.w = fmaf(w1, v1.w, acc.w);
            acc.x = fmaf(w2, v2.x, acc.x); acc.y = fmaf(w2, v2.y, acc.y);
            acc.z = fmaf(w2, v2.z, acc.z); acc.w = fmaf(w2, v2.w, acc.w);
            acc.x = fmaf(w3, v3.x, acc.x); acc.y = fmaf(w3, v3.y, acc.y);
            acc.z = fmaf(w3, v3.z, acc.z); acc.w = fmaf(w3, v3.w, acc.w);
        }
        for (; t + 2 <= cnt; t += 2) {  // pair: each half-wave one edge
            int e0 = t + half;
            int s0 = __shfl(s, e0);
            float w0 = __shfl(w, e0);
            float4 v0 = hp[(size_t)s0 * 32 + qc];
            acc.x = fmaf(w0, v0.x, acc.x); acc.y = fmaf(w0, v0.y, acc.y);
            acc.z = fmaf(w0, v0.z, acc.z); acc.w = fmaf(w0, v0.w, acc.w);
        }
        if (t < cnt) {  // single trailing edge: half 0 only
            int s0 = __shfl(s, t);
            float w0 = __shfl(w, t);
            if (half == 0) {
                float4 v0 = hp[(size_t)s0 * 32 + qc];
                acc.x = fmaf(w0, v0.x, acc.x); acc.y = fmaf(w0, v0.y, acc.y);
                acc.z = fmaf(w0, v0.z, acc.z); acc.w = fmaf(w0, v0.w, acc.w);
            }
        }
    }
    acc.x += __shfl_xor(acc.x, 32); acc.y += __shfl_xor(acc.y, 32);
    acc.z += __shfl_xor(acc.z, 32); acc.w += __shfl_xor(acc.w, 32);
    if (half == 0) {
        float inv = 1.f / den;  // deg >= 1 always (self-loop)
        float4 bv = ((const float4*)bias)[qc];
        float4 o;
        o.x = fmaxf(fmaf(acc.x, inv, bv.x), 0.f);
        o.y = fmaxf(fmaf(acc.y, inv, bv.y), 0.f);
        o.z = fmaxf(fmaf(acc.z, inv, bv.z), 0.f);
        o.w = fmaxf(fmaf(acc.w, inv, bv.w), 0.f);
        ((float4*)outp)[(size_t)n * 32 + qc] = o;
    }
}

// C=16 variant: 8 lane-groups x 8 lanes; each group owns every 8th edge
// (8 rows in flight per wave), cross-group shfl_xor reduce at the end.
__global__ __launch_bounds__(256) void agg16_kernel(
    const float* __restrict__ h, const int* __restrict__ off, const int* __restrict__ csr,
    const float* __restrict__ asv, const float* __restrict__ adv,
    const float* __restrict__ bias, float* __restrict__ outp) {
    int lane = threadIdx.x & 63;
    int n = (blockIdx.x * blockDim.x + threadIdx.x) >> 6;
    if (n >= N_NODES) return;
    int o0 = off[n], o1 = off[n + 1];
    float ad_n = adv[n];
    int g = lane >> 3, pr = lane & 7;  // group, pair-channel
    const float2* hp = (const float2*)h;  // row = 8 float2
    float m = -INFINITY, den = 0.f;
    float ax = 0.f, ay = 0.f;
    for (int base = o0; base < o1; base += 64) {
        int j = base + lane;
        bool valid = j < o1;
        int s = valid ? csr[j] : 0;
        float e = valid ? leaky(asv[s] + ad_n) : -INFINITY;
        float cm = e;
#pragma unroll
        for (int k = 32; k; k >>= 1) cm = fmaxf(cm, __shfl_xor(cm, k));
        float nm = fmaxf(m, cm);
        float rs = __expf(m - nm);
        den *= rs; ax *= rs; ay *= rs;
        float w = valid ? __expf(e - nm) : 0.f;
        float ws = w;
#pragma unroll
        for (int k = 32; k; k >>= 1) ws += __shfl_xor(ws, k);
        den += ws;
        m = nm;
        int cnt = min(64, o1 - base);
        for (int t = g; t < cnt; t += 8) {
            int st = __shfl(s, t);
            float wt = __shfl(w, t);
            float2 v = hp[(size_t)st * 8 + pr];
            ax = fmaf(wt, v.x, ax); ay = fmaf(wt, v.y, ay);
        }
    }
    ax += __shfl_xor(ax, 8);  ay += __shfl_xor(ay, 8);
    ax += __shfl_xor(ax, 16); ay += __shfl_xor(ay, 16);
    ax += __shfl_xor(ax, 32); ay += __shfl_xor(ay, 32);
    if (g == 0) {
        float inv = 1.f / den;
        float vx = fmaxf(fmaf(ax, inv, bias[pr * 2]), 0.f);
        float vy = fmaxf(fmaf(ay, inv, bias[pr * 2 + 1]), 0.f);
        ((float2*)outp)[(size_t)n * 8 + pr] = make_float2(vx, vy);
    }
}

// ---------------- global mean pool + sigmoid ----------------

__global__ void pool_partial_kernel(const float* __restrict__ h3, const int* __restrict__ batch,
                                    float* __restrict__ part) {
    __shared__ float sp[NG * 17];
    int tid = threadIdx.x;
    for (int i = tid; i < NG * 17; i += 256) sp[i] = 0.f;
    __syncthreads();
    int n = blockIdx.x * 256 + tid;
    if (n < N_NODES) {
        int g = batch[n];
        const float4* hv = (const float4*)(h3 + (size_t)n * NC);
#pragma unroll
        for (int j = 0; j < 4; ++j) {
            float4 v = hv[j];
            atomicAdd(&sp[g * 17 + j * 4 + 0], v.x);
            atomicAdd(&sp[g * 17 + j * 4 + 1], v.y);
            atomicAdd(&sp[g * 17 + j * 4 + 2], v.z);
            atomicAdd(&sp[g * 17 + j * 4 + 3], v.w);
        }
        atomicAdd(&sp[g * 17 + 16], 1.f);
    }
    __syncthreads();
    for (int i = tid; i < NG * 17; i += 256) part[(size_t)blockIdx.x * (NG * 17) + i] = sp[i];
}

__global__ void pool_final_kernel(const float* __restrict__ part, float* __restrict__ outp) {
    int tid = threadIdx.x;  // 1024 = 64 graphs x 16 classes
    int g = tid >> 4, c = tid & 15;
    float sum = 0.f, cnt = 0.f;
    for (int b = 0; b < NBLK_POOL; ++b) {
        sum += part[(size_t)b * (NG * 17) + g * 17 + c];
        cnt += part[(size_t)b * (NG * 17) + g * 17 + 16];
    }
    float v = sum / fmaxf(cnt, 1.f);
    outp[g * NC + c] = 1.f / (1.f + __expf(-v));
}

// ---------------- launch ----------------

extern "C" void kernel_launch(void* const* d_in, const int* in_sizes, int n_in,
                              void* d_out, int out_size, void* d_ws, size_t ws_size,
                              hipStream_t stream) {
    const float* x   = (const float*)d_in[0];
    const int*   ei  = (const int*)d_in[1];
    // d_in[2] edge_attr: unused by reference
    const int*   bat = (const int*)d_in[3];
    const float* W1  = (const float*)d_in[4];
    const float* as1 = (const float*)d_in[5];
    const float* ad1 = (const float*)d_in[6];
    const float* b1  = (const float*)d_in[7];
    const float* W2  = (const float*)d_in[8];
    const float* as2 = (const float*)d_in[9];
    const float* ad2 = (const float*)d_in[10];
    const float* b2  = (const float*)d_in[11];
    const float* W3  = (const float*)d_in[12];
    const float* as3 = (const float*)d_in[13];
    const float* ad3 = (const float*)d_in[14];
    const float* b3  = (const float*)d_in[15];
    float* outp = (float*)d_out;

    char* p = (char*)d_ws;
    auto carve = [&](size_t bytes) {
        char* r = p;
        p += (bytes + 255) & ~(size_t)255;
        return r;
    };
    int*   deg  = (int*)carve((size_t)N_NODES * 4);
    int*   off  = (int*)carve((size_t)(N_NODES + 1) * 4);
    int*   pos  = (int*)carve((size_t)N_NODES * 4);
    int*   csr  = (int*)carve((size_t)E_TOT * 4);
    int*   bsum = (int*)carve(256 * 4);
    float* hA   = (float*)carve((size_t)N_NODES * HID * 4);
    float* hB   = (float*)carve((size_t)N_NODES * HID * 4);
    float* asv  = (float*)carve((size_t)N_NODES * 4);
    float* adv  = (float*)carve((size_t)N_NODES * 4);
    float* part = (float*)carve((size_t)NBLK_POOL * NG * 17 * 4);

    const int scan_blocks = (N_NODES + 1023) / 1024;  // 49

    // CSR build
    zero_deg_kernel<<<(N_NODES + 255) / 256, 256, 0, stream>>>(deg);
    hist_kernel<<<2048, 256, 0, stream>>>(ei, deg);
    scan1_kernel<<<scan_blocks, 256, 0, stream>>>(deg, off, bsum);
    scan2_kernel<<<1, 256, 0, stream>>>(bsum, scan_blocks);
    scan3_kernel<<<(N_NODES + 255) / 256, 256, 0, stream>>>(off, bsum, pos);
    scatter_kernel<<<2048, 256, 0, stream>>>(ei, pos, csr);

    // Layer 1: 11 -> 128
    gemm1_kernel<<<N_NODES, 128, 0, stream>>>(x, W1, hA);
    alpha_kernel<HID><<<(N_NODES + 3) / 4, 256, 0, stream>>>(hA, as1, ad1, asv, adv);
    agg128_kernel<<<(N_NODES + 3) / 4, 256, 0, stream>>>(hA, off, csr, asv, adv, b1, hB);

    // Layer 2: 128 -> 128
    gemm2_kernel<<<(N_NODES + 15) / 16, 256, 0, stream>>>(hB, W2, hA);
    alpha_kernel<HID><<<(N_NODES + 3) / 4, 256, 0, stream>>>(hA, as2, ad2, asv, adv);
    agg128_kernel<<<(N_NODES + 3) / 4, 256, 0, stream>>>(hA, off, csr, asv, adv, b2, hB);

    // Layer 3: 128 -> 16
    gemm3_kernel<<<(N_NODES + 15) / 16, 256, 0, stream>>>(hB, W3, hA);  // hA reused as [N,16]
    alpha_kernel<NC><<<(N_NODES + 3) / 4, 256, 0, stream>>>(hA, as3, ad3, asv, adv);
    agg16_kernel<<<(N_NODES + 3) / 4, 256, 0, stream>>>(hA, off, csr, asv, adv, b3, hB);

    // Pool + sigmoid
    pool_partial_kernel<<<NBLK_POOL, 256, 0, stream>>>(hB, bat, part);
    pool_final_kernel<<<1, 1024, 0, stream>>>(part, outp);
}

// Round 4
// 425.275 us; speedup vs baseline: 1.2679x; 1.1600x over previous
//
#include <hip/hip_runtime.h>
#include <hip/hip_bf16.h>
#include <math.h>

#define N_NODES 50000
#define N_EDGES 800000
#define F_IN    11
#define HID     128
#define NC      16
#define NG      64
#define E_TOT   (N_EDGES + N_NODES)   // 850000 edges incl. self-loops
#define NBLK_POOL ((N_NODES + 255) / 256)  // 196
#define NEG_SLOPE 0.2f

#define NB   ((N_NODES + 63) >> 6)    // 782 buckets of 64 dst each
#define BCAP 4096                      // LDS pair-staging capacity in csr_finalize

__device__ __forceinline__ float leaky(float x) { return x >= 0.f ? x : NEG_SLOPE * x; }

// ---------------- bucketed CSR build (dst-sorted, coalesced writes) ----------------
// Replaces per-edge atomic scatter (was 54.7MB of bounced line evictions for a
// 3.4MB csr): bin edges into 782 dst-buckets (LDS-privatized counts, block-claimed
// ranges), then finalize each bucket's CSR slice as one contiguous L2-resident write.

__global__ void zero_nb_kernel(int* __restrict__ gcount) {
    int i = threadIdx.x;
    if (i < NB) gcount[i] = 0;
}

// count regular edges per bucket (self-loops added analytically in scanB)
__global__ __launch_bounds__(256) void bucket_hist_kernel(const int* __restrict__ ei,
                                                          int* __restrict__ gcount) {
    __shared__ int cnt[NB];
    int tid = threadIdx.x;
    for (int i = tid; i < NB; i += 256) cnt[i] = 0;
    __syncthreads();
    int e0 = blockIdx.x * 4096 + tid;
#pragma unroll
    for (int k = 0; k < 16; ++k) {
        int e = e0 + k * 256;
        if (e < N_EDGES) atomicAdd(&cnt[ei[N_EDGES + e] >> 6], 1);
    }
    __syncthreads();
    for (int i = tid; i < NB; i += 256)
        if (cnt[i]) atomicAdd(&gcount[i], cnt[i]);
}

// exclusive scan over NB bucket counts (+self-loop contribution); init cursors
__global__ void scanB_kernel(const int* __restrict__ gcount, int* __restrict__ bOff,
                             int* __restrict__ gcur) {
    __shared__ int ls[1024];
    int tid = threadIdx.x;
    int v = 0;
    if (tid < NB) {
        int sl = N_NODES - (tid << 6);         // self-loops in this bucket
        sl = sl > 64 ? 64 : sl;
        v = gcount[tid] + sl;
    }
    ls[tid] = v;
    __syncthreads();
    for (int ofs = 1; ofs < 1024; ofs <<= 1) {
        int x = (tid >= ofs) ? ls[tid - ofs] : 0;
        __syncthreads();
        ls[tid] += x;
        __syncthreads();
    }
    int excl = (tid > 0) ? ls[tid - 1] : 0;
    if (tid < NB) { bOff[tid] = excl; gcur[tid] = excl; }
    if (tid == 0) bOff[NB] = E_TOT;
}

// scatter (src,dst) pairs into bucket-grouped storage; block claims a per-bucket
// range with ONE atomic, then fills consecutive slots -> write-combinable in L2.
__global__ __launch_bounds__(256) void bucket_scatter_kernel(const int* __restrict__ ei,
                                                             int* __restrict__ gcur,
                                                             uint2* __restrict__ pairs) {
    __shared__ int cnt[NB];
    __shared__ int base[NB];
    int tid = threadIdx.x;
    for (int i = tid; i < NB; i += 256) cnt[i] = 0;
    __syncthreads();
    int s[16], d[16];
    int e0 = blockIdx.x * 4096 + tid;
#pragma unroll
    for (int k = 0; k < 16; ++k) {
        int e = e0 + k * 256;
        if (e < N_EDGES) { s[k] = ei[e]; d[k] = ei[N_EDGES + e]; }
        else if (e < E_TOT) { s[k] = d[k] = e - N_EDGES; }   // self-loop
        else d[k] = -1;
        if (d[k] >= 0) atomicAdd(&cnt[d[k] >> 6], 1);
    }
    __syncthreads();
    for (int i = tid; i < NB; i += 256)
        base[i] = cnt[i] ? atomicAdd(&gcur[i], cnt[i]) : 0;
    __syncthreads();
    for (int i = tid; i < NB; i += 256) cnt[i] = 0;
    __syncthreads();
#pragma unroll
    for (int k = 0; k < 16; ++k) {
        if (d[k] >= 0) {
            int b = d[k] >> 6;
            int r = atomicAdd(&cnt[b], 1);
            pairs[base[b] + r] = make_uint2((unsigned)s[k], (unsigned)d[k]);
        }
    }
}

// one block per bucket: local hist+scan over 64 dsts, emit off[] and the
// bucket's contiguous csr slice.
__global__ __launch_bounds__(256) void csr_finalize_kernel(const uint2* __restrict__ pairs,
                                                           const int* __restrict__ bOff,
                                                           int* __restrict__ off,
                                                           int* __restrict__ csr) {
    __shared__ uint2 lp[BCAP];      // 32KB staging
    __shared__ int deg[64], offs[65], cnt[64];
    int b = blockIdx.x, tid = threadIdx.x;
    int d0 = b << 6;
    int nd = N_NODES - d0; nd = nd > 64 ? 64 : nd;
    int lo = bOff[b], hi = bOff[b + 1], n = hi - lo;
    if (tid < 64) { deg[tid] = 0; cnt[tid] = 0; }
    __syncthreads();
    bool staged = (n <= BCAP);
    for (int i = tid; i < n; i += 256) {
        uint2 p = pairs[lo + i];
        if (staged) lp[i] = p;
        atomicAdd(&deg[(int)p.y - d0], 1);
    }
    __syncthreads();
    if (tid == 0) {
        int a = 0;
#pragma unroll
        for (int i = 0; i < 64; ++i) { offs[i] = a; a += deg[i]; }
        offs[64] = a;
    }
    __syncthreads();
    if (tid < nd) off[d0 + tid] = lo + offs[tid];
    if (b == (int)gridDim.x - 1 && tid == 0) off[N_NODES] = E_TOT;
    for (int i = tid; i < n; i += 256) {
        uint2 p = staged ? lp[i] : pairs[lo + i];
        int ld = (int)p.y - d0;
        int r = atomicAdd(&cnt[ld], 1);
        csr[lo + offs[ld] + r] = (int)p.x;   // contiguous ~4-5KB region per block
    }
}

// ---------------- GEMMs (f32 VALU; no fp32 MFMA on CDNA4) ----------------

// x[N,11] @ W[11,128] -> h[N,128]; one row per block of 128 threads
__global__ void gemm1_kernel(const float* __restrict__ x, const float* __restrict__ W,
                             float* __restrict__ h) {
    __shared__ float xr[F_IN];
    int row = blockIdx.x;
    int t = threadIdx.x;
    if (t < F_IN) xr[t] = x[row * F_IN + t];
    __syncthreads();
    float acc = 0.f;
#pragma unroll
    for (int k = 0; k < F_IN; ++k) acc = fmaf(xr[k], W[k * HID + t], acc);
    h[(size_t)row * HID + t] = acc;
}

// A[N,128] @ W[128,128] -> out[N,128]; block 256, 16 rows/block, 8 rows/thread-regtile
__global__ __launch_bounds__(256) void gemm2_kernel(const float* __restrict__ A,
                                                    const float* __restrict__ W,
                                                    float* __restrict__ outp) {
    __shared__ float hs[16][HID];   // reads are wave-uniform broadcasts -> no conflicts
    int tid = threadIdx.x;
    int row0 = blockIdx.x * 16;
    for (int i = tid; i < 16 * HID; i += 256) {
        int r = i >> 7, c = i & 127;
        int gr = row0 + r;
        hs[r][c] = (gr < N_NODES) ? A[(size_t)gr * HID + c] : 0.f;
    }
    __syncthreads();
    int col = tid & 127, rg = tid >> 7;
    float acc[8] = {0.f, 0.f, 0.f, 0.f, 0.f, 0.f, 0.f, 0.f};
    for (int k4 = 0; k4 < HID / 4; ++k4) {
        float4 hv[8];
#pragma unroll
        for (int r = 0; r < 8; ++r)
            hv[r] = *(const float4*)&hs[rg * 8 + r][k4 * 4];
#pragma unroll
        for (int kk = 0; kk < 4; ++kk) {
            float w = W[(k4 * 4 + kk) * HID + col];
#pragma unroll
            for (int r = 0; r < 8; ++r)
                acc[r] = fmaf(((const float*)&hv[r])[kk], w, acc[r]);
        }
    }
#pragma unroll
    for (int r = 0; r < 8; ++r) {
        int gr = row0 + rg * 8 + r;
        if (gr < N_NODES) outp[(size_t)gr * HID + col] = acc[r];
    }
}

// A[N,128] @ W[128,16] -> out[N,16]; block 256 = 16 rows x 16 cols
__global__ __launch_bounds__(256) void gemm3_kernel(const float* __restrict__ A,
                                                    const float* __restrict__ W,
                                                    float* __restrict__ outp) {
    __shared__ float hs[16][HID + 1];  // pad: 16 distinct rows read per k
    int tid = threadIdx.x;
    int row0 = blockIdx.x * 16;
    for (int i = tid; i < 16 * HID; i += 256) {
        int r = i >> 7, c = i & 127;
        int gr = row0 + r;
        hs[r][c] = (gr < N_NODES) ? A[(size_t)gr * HID + c] : 0.f;
    }
    __syncthreads();
    int col = tid & 15, r = tid >> 4;
    float acc = 0.f;
#pragma unroll 4
    for (int k = 0; k < HID; ++k) acc = fmaf(hs[r][k], W[k * NC + col], acc);
    int gr = row0 + r;
    if (gr < N_NODES) outp[(size_t)gr * NC + col] = acc;
}

// ---------------- attention logits: asv[n] = h[n,:]·a_src, adv[n] = h[n,:]·a_dst ----------------

template <int C>
__global__ void alpha_kernel(const float* __restrict__ h, const float* __restrict__ a_s,
                             const float* __restrict__ a_d, float* __restrict__ asv,
                             float* __restrict__ adv) {
    int lane = threadIdx.x & 63;
    int n = (blockIdx.x * blockDim.x + threadIdx.x) >> 6;
    if (n >= N_NODES) return;
    float ps = 0.f, pd = 0.f;
#pragma unroll
    for (int c = lane; c < C; c += 64) {
        float v = h[(size_t)n * C + c];
        ps = fmaf(v, a_s[c], ps);
        pd = fmaf(v, a_d[c], pd);
    }
#pragma unroll
    for (int k = 32; k; k >>= 1) {
        ps += __shfl_xor(ps, k);
        pd += __shfl_xor(pd, k);
    }
    if (lane == 0) { asv[n] = ps; adv[n] = pd; }
}

// ---------------- fused segment-softmax + weighted aggregation ----------------
// One wave per dst node. Phase 1 (per 64-edge batch): edges lane-parallel
// (online max / exp / denom via shfl reductions). Phase 2: half-wave per edge
// (32 lanes x float4 = 512B row), 4 edges unrolled -> 4 rows in flight/lane.

__global__ __launch_bounds__(256) void agg128_kernel(
    const float* __restrict__ h, const int* __restrict__ off, const int* __restrict__ csr,
    const float* __restrict__ asv, const float* __restrict__ adv,
    const float* __restrict__ bias, float* __restrict__ outp) {
    int lane = threadIdx.x & 63;
    int n = (blockIdx.x * blockDim.x + threadIdx.x) >> 6;
    if (n >= N_NODES) return;
    int o0 = off[n], o1 = off[n + 1];
    float ad_n = adv[n];
    int half = lane >> 5;        // which edge of a pair this half-wave handles
    int qc = lane & 31;          // float4 index within the 128-ch row
    const float4* hp = (const float4*)h;
    float m = -INFINITY, den = 0.f;
    float4 acc = make_float4(0.f, 0.f, 0.f, 0.f);
    for (int base = o0; base < o1; base += 64) {
        int j = base + lane;
        bool valid = j < o1;
        int s = valid ? csr[j] : 0;
        float e = valid ? leaky(asv[s] + ad_n) : -INFINITY;
        float cm = e;
#pragma unroll
        for (int k = 32; k; k >>= 1) cm = fmaxf(cm, __shfl_xor(cm, k));
        float nm = fmaxf(m, cm);
        float rs = __expf(m - nm);  // m==-inf first batch -> 0, acc already 0
        den *= rs; acc.x *= rs; acc.y *= rs; acc.z *= rs; acc.w *= rs;
        float w = valid ? __expf(e - nm) : 0.f;
        float ws = w;
#pragma unroll
        for (int k = 32; k; k >>= 1) ws += __shfl_xor(ws, k);
        den += ws;
        m = nm;
        int cnt = min(64, o1 - base);
        int t = 0;
        for (; t + 8 <= cnt; t += 8) {  // 8 edges per iter: 4 rows in flight per lane
            int e0 = t + half, e1 = t + 2 + half, e2 = t + 4 + half, e3 = t + 6 + half;
            int s0 = __shfl(s, e0), s1 = __shfl(s, e1), s2 = __shfl(s, e2), s3 = __shfl(s, e3);
            float w0 = __shfl(w, e0), w1 = __shfl(w, e1), w2 = __shfl(w, e2), w3 = __shfl(w, e3);
            float4 v0 = hp[(size_t)s0 * 32 + qc];
            float4 v1 = hp[(size_t)s1 * 32 + qc];
            float4 v2 = hp[(size_t)s2 * 32 + qc];
            float4 v3 = hp[(size_t)s3 * 32 + qc];
            acc.x = fmaf(w0, v0.x, acc.x); acc.y = fmaf(w0, v0.y, acc.y);
            acc.z = fmaf(w0, v0.z, acc.z); acc.w = fmaf(w0, v0.w, acc.w);
            acc.x = fmaf(w1, v1.x, acc.x); acc.y = fmaf(w1, v1.y, acc.y);
            acc.z = fmaf(w1, v1.z, acc.z); acc.w = fmaf(w1, v1.w, acc.w);
            acc.x = fmaf(w2, v2.x, acc.x); acc.y = fmaf(w2, v2.y, acc.y);
            acc.z = fmaf(w2, v2.z, acc.z); acc.w = fmaf(w2, v2.w, acc.w);
            acc.x = fmaf(w3, v3.x, acc.x); acc.y = fmaf(w3, v3.y, acc.y);
            acc.z = fmaf(w3, v3.z, acc.z); acc.w = fmaf(w3, v3.w, acc.w);
        }
        for (; t + 2 <= cnt; t += 2) {  // pair: each half-wave one edge
            int e0 = t + half;
            int s0 = __shfl(s, e0);
            float w0 = __shfl(w, e0);
            float4 v0 = hp[(size_t)s0 * 32 + qc];
            acc.x = fmaf(w0, v0.x, acc.x); acc.y = fmaf(w0, v0.y, acc.y);
            acc.z = fmaf(w0, v0.z, acc.z); acc.w = fmaf(w0, v0.w, acc.w);
        }
        if (t < cnt) {  // single trailing edge: half 0 only
            int s0 = __shfl(s, t);
            float w0 = __shfl(w, t);
            if (half == 0) {
                float4 v0 = hp[(size_t)s0 * 32 + qc];
                acc.x = fmaf(w0, v0.x, acc.x); acc.y = fmaf(w0, v0.y, acc.y);
                acc.z = fmaf(w0, v0.z, acc.z); acc.w = fmaf(w0, v0.w, acc.w);
            }
        }
    }
    acc.x += __shfl_xor(acc.x, 32); acc.y += __shfl_xor(acc.y, 32);
    acc.z += __shfl_xor(acc.z, 32); acc.w += __shfl_xor(acc.w, 32);
    if (half == 0) {
        float inv = 1.f / den;  // deg >= 1 always (self-loop)
        float4 bv = ((const float4*)bias)[qc];
        float4 o;
        o.x = fmaxf(fmaf(acc.x, inv, bv.x), 0.f);
        o.y = fmaxf(fmaf(acc.y, inv, bv.y), 0.f);
        o.z = fmaxf(fmaf(acc.z, inv, bv.z), 0.f);
        o.w = fmaxf(fmaf(acc.w, inv, bv.w), 0.f);
        ((float4*)outp)[(size_t)n * 32 + qc] = o;
    }
}

// C=16 variant: 8 lane-groups x 8 lanes; each group owns every 8th edge
// (8 rows in flight per wave), cross-group shfl_xor reduce at the end.
__global__ __launch_bounds__(256) void agg16_kernel(
    const float* __restrict__ h, const int* __restrict__ off, const int* __restrict__ csr,
    const float* __restrict__ asv, const float* __restrict__ adv,
    const float* __restrict__ bias, float* __restrict__ outp) {
    int lane = threadIdx.x & 63;
    int n = (blockIdx.x * blockDim.x + threadIdx.x) >> 6;
    if (n >= N_NODES) return;
    int o0 = off[n], o1 = off[n + 1];
    float ad_n = adv[n];
    int g = lane >> 3, pr = lane & 7;  // group, pair-channel
    const float2* hp = (const float2*)h;  // row = 8 float2
    float m = -INFINITY, den = 0.f;
    float ax = 0.f, ay = 0.f;
    for (int base = o0; base < o1; base += 64) {
        int j = base + lane;
        bool valid = j < o1;
        int s = valid ? csr[j] : 0;
        float e = valid ? leaky(asv[s] + ad_n) : -INFINITY;
        float cm = e;
#pragma unroll
        for (int k = 32; k; k >>= 1) cm = fmaxf(cm, __shfl_xor(cm, k));
        float nm = fmaxf(m, cm);
        float rs = __expf(m - nm);
        den *= rs; ax *= rs; ay *= rs;
        float w = valid ? __expf(e - nm) : 0.f;
        float ws = w;
#pragma unroll
        for (int k = 32; k; k >>= 1) ws += __shfl_xor(ws, k);
        den += ws;
        m = nm;
        int cnt = min(64, o1 - base);
        for (int t = g; t < cnt; t += 8) {
            int st = __shfl(s, t);
            float wt = __shfl(w, t);
            float2 v = hp[(size_t)st * 8 + pr];
            ax = fmaf(wt, v.x, ax); ay = fmaf(wt, v.y, ay);
        }
    }
    ax += __shfl_xor(ax, 8);  ay += __shfl_xor(ay, 8);
    ax += __shfl_xor(ax, 16); ay += __shfl_xor(ay, 16);
    ax += __shfl_xor(ax, 32); ay += __shfl_xor(ay, 32);
    if (g == 0) {
        float inv = 1.f / den;
        float vx = fmaxf(fmaf(ax, inv, bias[pr * 2]), 0.f);
        float vy = fmaxf(fmaf(ay, inv, bias[pr * 2 + 1]), 0.f);
        ((float2*)outp)[(size_t)n * 8 + pr] = make_float2(vx, vy);
    }
}

// ---------------- global mean pool + sigmoid ----------------

__global__ void pool_partial_kernel(const float* __restrict__ h3, const int* __restrict__ batch,
                                    float* __restrict__ part) {
    __shared__ float sp[NG * 17];
    int tid = threadIdx.x;
    for (int i = tid; i < NG * 17; i += 256) sp[i] = 0.f;
    __syncthreads();
    int n = blockIdx.x * 256 + tid;
    if (n < N_NODES) {
        int g = batch[n];
        const float4* hv = (const float4*)(h3 + (size_t)n * NC);
#pragma unroll
        for (int j = 0; j < 4; ++j) {
            float4 v = hv[j];
            atomicAdd(&sp[g * 17 + j * 4 + 0], v.x);
            atomicAdd(&sp[g * 17 + j * 4 + 1], v.y);
            atomicAdd(&sp[g * 17 + j * 4 + 2], v.z);
            atomicAdd(&sp[g * 17 + j * 4 + 3], v.w);
        }
        atomicAdd(&sp[g * 17 + 16], 1.f);
    }
    __syncthreads();
    for (int i = tid; i < NG * 17; i += 256) part[(size_t)blockIdx.x * (NG * 17) + i] = sp[i];
}

__global__ void pool_final_kernel(const float* __restrict__ part, float* __restrict__ outp) {
    int tid = threadIdx.x;  // 1024 = 64 graphs x 16 classes
    int g = tid >> 4, c = tid & 15;
    float sum = 0.f, cnt = 0.f;
    for (int b = 0; b < NBLK_POOL; ++b) {
        sum += part[(size_t)b * (NG * 17) + g * 17 + c];
        cnt += part[(size_t)b * (NG * 17) + g * 17 + 16];
    }
    float v = sum / fmaxf(cnt, 1.f);
    outp[g * NC + c] = 1.f / (1.f + __expf(-v));
}

// ---------------- launch ----------------

extern "C" void kernel_launch(void* const* d_in, const int* in_sizes, int n_in,
                              void* d_out, int out_size, void* d_ws, size_t ws_size,
                              hipStream_t stream) {
    const float* x   = (const float*)d_in[0];
    const int*   ei  = (const int*)d_in[1];
    // d_in[2] edge_attr: unused by reference
    const int*   bat = (const int*)d_in[3];
    const float* W1  = (const float*)d_in[4];
    const float* as1 = (const float*)d_in[5];
    const float* ad1 = (const float*)d_in[6];
    const float* b1  = (const float*)d_in[7];
    const float* W2  = (const float*)d_in[8];
    const float* as2 = (const float*)d_in[9];
    const float* ad2 = (const float*)d_in[10];
    const float* b2  = (const float*)d_in[11];
    const float* W3  = (const float*)d_in[12];
    const float* as3 = (const float*)d_in[13];
    const float* ad3 = (const float*)d_in[14];
    const float* b3  = (const float*)d_in[15];
    float* outp = (float*)d_out;

    char* p = (char*)d_ws;
    auto carve = [&](size_t bytes) {
        char* r = p;
        p += (bytes + 255) & ~(size_t)255;
        return r;
    };
    int*   off    = (int*)carve((size_t)(N_NODES + 1) * 4);
    int*   csr    = (int*)carve((size_t)E_TOT * 4);
    int*   gcount = (int*)carve((size_t)NB * 4);
    int*   bOff   = (int*)carve((size_t)(NB + 1) * 4);
    int*   gcur   = (int*)carve((size_t)NB * 4);
    float* hA     = (float*)carve((size_t)N_NODES * HID * 4);
    float* hB     = (float*)carve((size_t)N_NODES * HID * 4);
    float* asv    = (float*)carve((size_t)N_NODES * 4);
    float* adv    = (float*)carve((size_t)N_NODES * 4);
    float* part   = (float*)carve((size_t)NBLK_POOL * NG * 17 * 4);
    // pairs (6.8MB) aliases hB (25.6MB): last read of pairs is csr_finalize,
    // which completes (stream-ordered) before agg128-L1 first writes hB.
    uint2* pairs  = (uint2*)hB;

    // CSR build (bucketed)
    zero_nb_kernel<<<1, 1024, 0, stream>>>(gcount);
    bucket_hist_kernel<<<(N_EDGES + 4095) / 4096, 256, 0, stream>>>(ei, gcount);
    scanB_kernel<<<1, 1024, 0, stream>>>(gcount, bOff, gcur);
    bucket_scatter_kernel<<<(E_TOT + 4095) / 4096, 256, 0, stream>>>(ei, gcur, pairs);
    csr_finalize_kernel<<<NB, 256, 0, stream>>>(pairs, bOff, off, csr);

    // Layer 1: 11 -> 128
    gemm1_kernel<<<N_NODES, 128, 0, stream>>>(x, W1, hA);
    alpha_kernel<HID><<<(N_NODES + 3) / 4, 256, 0, stream>>>(hA, as1, ad1, asv, adv);
    agg128_kernel<<<(N_NODES + 3) / 4, 256, 0, stream>>>(hA, off, csr, asv, adv, b1, hB);

    // Layer 2: 128 -> 128
    gemm2_kernel<<<(N_NODES + 15) / 16, 256, 0, stream>>>(hB, W2, hA);
    alpha_kernel<HID><<<(N_NODES + 3) / 4, 256, 0, stream>>>(hA, as2, ad2, asv, adv);
    agg128_kernel<<<(N_NODES + 3) / 4, 256, 0, stream>>>(hA, off, csr, asv, adv, b2, hB);

    // Layer 3: 128 -> 16
    gemm3_kernel<<<(N_NODES + 15) / 16, 256, 0, stream>>>(hB, W3, hA);  // hA reused as [N,16]
    alpha_kernel<NC><<<(N_NODES + 3) / 4, 256, 0, stream>>>(hA, as3, ad3, asv, adv);
    agg16_kernel<<<(N_NODES + 3) / 4, 256, 0, stream>>>(hA, off, csr, asv, adv, b3, hB);

    // Pool + sigmoid
    pool_partial_kernel<<<NBLK_POOL, 256, 0, stream>>>(hB, bat, part);
    pool_final_kernel<<<1, 1024, 0, stream>>>(part, outp);
}

// Round 5
// 393.597 us; speedup vs baseline: 1.3700x; 1.0805x over previous
//
#include <hip/hip_runtime.h>
#include <hip/hip_bf16.h>
#include <hip/hip_fp16.h>
#include <math.h>

#define N_NODES 50000
#define N_EDGES 800000
#define F_IN    11
#define HID     128
#define NC      16
#define NG      64
#define E_TOT   (N_EDGES + N_NODES)   // 850000 edges incl. self-loops
#define NBLK_POOL ((N_NODES + 255) / 256)  // 196
#define NEG_SLOPE 0.2f

#define NB   ((N_NODES + 63) >> 6)    // 782 buckets of 64 dst each
#define BCAP 4096                      // LDS pair-staging capacity in csr_finalize

typedef _Float16 half_t;
typedef __attribute__((ext_vector_type(4))) _Float16 half4;

__device__ __forceinline__ float leaky(float x) { return x >= 0.f ? x : NEG_SLOPE * x; }

// ---------------- bucketed CSR build (dst-sorted, coalesced writes) ----------------

__global__ void zero_nb_kernel(int* __restrict__ gcount) {
    int i = threadIdx.x;
    if (i < NB) gcount[i] = 0;
}

// count regular edges per bucket (self-loops added analytically in scanB)
__global__ __launch_bounds__(256) void bucket_hist_kernel(const int* __restrict__ ei,
                                                          int* __restrict__ gcount) {
    __shared__ int cnt[NB];
    int tid = threadIdx.x;
    for (int i = tid; i < NB; i += 256) cnt[i] = 0;
    __syncthreads();
    int e0 = blockIdx.x * 4096 + tid;
#pragma unroll
    for (int k = 0; k < 16; ++k) {
        int e = e0 + k * 256;
        if (e < N_EDGES) atomicAdd(&cnt[ei[N_EDGES + e] >> 6], 1);
    }
    __syncthreads();
    for (int i = tid; i < NB; i += 256)
        if (cnt[i]) atomicAdd(&gcount[i], cnt[i]);
}

// exclusive scan over NB bucket counts (+self-loop contribution); init cursors
__global__ void scanB_kernel(const int* __restrict__ gcount, int* __restrict__ bOff,
                             int* __restrict__ gcur) {
    __shared__ int ls[1024];
    int tid = threadIdx.x;
    int v = 0;
    if (tid < NB) {
        int sl = N_NODES - (tid << 6);         // self-loops in this bucket
        sl = sl > 64 ? 64 : sl;
        v = gcount[tid] + sl;
    }
    ls[tid] = v;
    __syncthreads();
    for (int ofs = 1; ofs < 1024; ofs <<= 1) {
        int x = (tid >= ofs) ? ls[tid - ofs] : 0;
        __syncthreads();
        ls[tid] += x;
        __syncthreads();
    }
    int excl = (tid > 0) ? ls[tid - 1] : 0;
    if (tid < NB) { bOff[tid] = excl; gcur[tid] = excl; }
    if (tid == 0) bOff[NB] = E_TOT;
}

// scatter (src,dst) pairs into bucket-grouped storage; block claims a per-bucket
// range with ONE atomic, then fills consecutive slots -> write-combinable in L2.
__global__ __launch_bounds__(256) void bucket_scatter_kernel(const int* __restrict__ ei,
                                                             int* __restrict__ gcur,
                                                             uint2* __restrict__ pairs) {
    __shared__ int cnt[NB];
    __shared__ int base[NB];
    int tid = threadIdx.x;
    for (int i = tid; i < NB; i += 256) cnt[i] = 0;
    __syncthreads();
    int s[16], d[16];
    int e0 = blockIdx.x * 4096 + tid;
#pragma unroll
    for (int k = 0; k < 16; ++k) {
        int e = e0 + k * 256;
        if (e < N_EDGES) { s[k] = ei[e]; d[k] = ei[N_EDGES + e]; }
        else if (e < E_TOT) { s[k] = d[k] = e - N_EDGES; }   // self-loop
        else d[k] = -1;
        if (d[k] >= 0) atomicAdd(&cnt[d[k] >> 6], 1);
    }
    __syncthreads();
    for (int i = tid; i < NB; i += 256)
        base[i] = cnt[i] ? atomicAdd(&gcur[i], cnt[i]) : 0;
    __syncthreads();
    for (int i = tid; i < NB; i += 256) cnt[i] = 0;
    __syncthreads();
#pragma unroll
    for (int k = 0; k < 16; ++k) {
        if (d[k] >= 0) {
            int b = d[k] >> 6;
            int r = atomicAdd(&cnt[b], 1);
            pairs[base[b] + r] = make_uint2((unsigned)s[k], (unsigned)d[k]);
        }
    }
}

// one block per bucket: local hist+scan over 64 dsts, emit off[] and the
// bucket's contiguous csr slice.
__global__ __launch_bounds__(256) void csr_finalize_kernel(const uint2* __restrict__ pairs,
                                                           const int* __restrict__ bOff,
                                                           int* __restrict__ off,
                                                           int* __restrict__ csr) {
    __shared__ uint2 lp[BCAP];      // 32KB staging
    __shared__ int deg[64], offs[65], cnt[64];
    int b = blockIdx.x, tid = threadIdx.x;
    int d0 = b << 6;
    int nd = N_NODES - d0; nd = nd > 64 ? 64 : nd;
    int lo = bOff[b], hi = bOff[b + 1], n = hi - lo;
    if (tid < 64) { deg[tid] = 0; cnt[tid] = 0; }
    __syncthreads();
    bool staged = (n <= BCAP);
    for (int i = tid; i < n; i += 256) {
        uint2 p = pairs[lo + i];
        if (staged) lp[i] = p;
        atomicAdd(&deg[(int)p.y - d0], 1);
    }
    __syncthreads();
    if (tid == 0) {
        int a = 0;
#pragma unroll
        for (int i = 0; i < 64; ++i) { offs[i] = a; a += deg[i]; }
        offs[64] = a;
    }
    __syncthreads();
    if (tid < nd) off[d0 + tid] = lo + offs[tid];
    if (b == (int)gridDim.x - 1 && tid == 0) off[N_NODES] = E_TOT;
    for (int i = tid; i < n; i += 256) {
        uint2 p = staged ? lp[i] : pairs[lo + i];
        int ld = (int)p.y - d0;
        int r = atomicAdd(&cnt[ld], 1);
        csr[lo + offs[ld] + r] = (int)p.x;   // contiguous ~4-5KB region per block
    }
}

// ---------------- GEMMs (f32 VALU; no fp32 MFMA on CDNA4) ----------------
// Epilogues also store an fp16 copy of h for the gather path (halves agg bytes;
// fp16 not bf16: |h| small, 10-bit mantissa keeps gather error ~5e-4 relative).

// x[N,11] @ W[11,128] -> h[N,128]; one row per block of 128 threads
__global__ void gemm1_kernel(const float* __restrict__ x, const float* __restrict__ W,
                             float* __restrict__ h, half_t* __restrict__ h16) {
    __shared__ float xr[F_IN];
    int row = blockIdx.x;
    int t = threadIdx.x;
    if (t < F_IN) xr[t] = x[row * F_IN + t];
    __syncthreads();
    float acc = 0.f;
#pragma unroll
    for (int k = 0; k < F_IN; ++k) acc = fmaf(xr[k], W[k * HID + t], acc);
    h[(size_t)row * HID + t] = acc;
    h16[(size_t)row * HID + t] = (half_t)acc;
}

// A[N,128] @ W[128,128] -> out[N,128]; block 256, 16 rows/block, 8 rows/thread-regtile
__global__ __launch_bounds__(256) void gemm2_kernel(const float* __restrict__ A,
                                                    const float* __restrict__ W,
                                                    float* __restrict__ outp,
                                                    half_t* __restrict__ h16) {
    __shared__ float hs[16][HID];   // reads are wave-uniform broadcasts -> no conflicts
    int tid = threadIdx.x;
    int row0 = blockIdx.x * 16;
    for (int i = tid; i < 16 * HID; i += 256) {
        int r = i >> 7, c = i & 127;
        int gr = row0 + r;
        hs[r][c] = (gr < N_NODES) ? A[(size_t)gr * HID + c] : 0.f;
    }
    __syncthreads();
    int col = tid & 127, rg = tid >> 7;
    float acc[8] = {0.f, 0.f, 0.f, 0.f, 0.f, 0.f, 0.f, 0.f};
    for (int k4 = 0; k4 < HID / 4; ++k4) {
        float4 hv[8];
#pragma unroll
        for (int r = 0; r < 8; ++r)
            hv[r] = *(const float4*)&hs[rg * 8 + r][k4 * 4];
#pragma unroll
        for (int kk = 0; kk < 4; ++kk) {
            float w = W[(k4 * 4 + kk) * HID + col];
#pragma unroll
            for (int r = 0; r < 8; ++r)
                acc[r] = fmaf(((const float*)&hv[r])[kk], w, acc[r]);
        }
    }
#pragma unroll
    for (int r = 0; r < 8; ++r) {
        int gr = row0 + rg * 8 + r;
        if (gr < N_NODES) {
            outp[(size_t)gr * HID + col] = acc[r];
            h16[(size_t)gr * HID + col] = (half_t)acc[r];
        }
    }
}

// A[N,128] @ W[128,16] -> out[N,16]; block 256 = 16 rows x 16 cols
__global__ __launch_bounds__(256) void gemm3_kernel(const float* __restrict__ A,
                                                    const float* __restrict__ W,
                                                    float* __restrict__ outp) {
    __shared__ float hs[16][HID + 1];  // pad: 16 distinct rows read per k
    int tid = threadIdx.x;
    int row0 = blockIdx.x * 16;
    for (int i = tid; i < 16 * HID; i += 256) {
        int r = i >> 7, c = i & 127;
        int gr = row0 + r;
        hs[r][c] = (gr < N_NODES) ? A[(size_t)gr * HID + c] : 0.f;
    }
    __syncthreads();
    int col = tid & 15, r = tid >> 4;
    float acc = 0.f;
#pragma unroll 4
    for (int k = 0; k < HID; ++k) acc = fmaf(hs[r][k], W[k * NC + col], acc);
    int gr = row0 + r;
    if (gr < N_NODES) outp[(size_t)gr * NC + col] = acc;
}

// ---------------- attention logits: asv[n] = h[n,:]·a_src, adv[n] = h[n,:]·a_dst ----------------
// Stays on f32 h: logit precision feeds exp() -> keep full accuracy.

template <int C>
__global__ void alpha_kernel(const float* __restrict__ h, const float* __restrict__ a_s,
                             const float* __restrict__ a_d, float* __restrict__ asv,
                             float* __restrict__ adv) {
    int lane = threadIdx.x & 63;
    int n = (blockIdx.x * blockDim.x + threadIdx.x) >> 6;
    if (n >= N_NODES) return;
    float ps = 0.f, pd = 0.f;
#pragma unroll
    for (int c = lane; c < C; c += 64) {
        float v = h[(size_t)n * C + c];
        ps = fmaf(v, a_s[c], ps);
        pd = fmaf(v, a_d[c], pd);
    }
#pragma unroll
    for (int k = 32; k; k >>= 1) {
        ps += __shfl_xor(ps, k);
        pd += __shfl_xor(pd, k);
    }
    if (lane == 0) { asv[n] = ps; adv[n] = pd; }
}

// ---------------- fused segment-softmax + weighted aggregation ----------------
// One wave per dst node. Phase 1 (per 64-edge batch): edges lane-parallel
// (online max / exp / denom via shfl reductions). Phase 2: half-wave per edge
// (32 lanes x half4 = 256B fp16 row), 4 edges unrolled -> 4 rows in flight/lane.
// Gather reads fp16 rows (halves L2-miss bytes); accumulate f32; output f32.

__global__ __launch_bounds__(256) void agg128_kernel(
    const half_t* __restrict__ h16, const int* __restrict__ off, const int* __restrict__ csr,
    const float* __restrict__ asv, const float* __restrict__ adv,
    const float* __restrict__ bias, float* __restrict__ outp) {
    int lane = threadIdx.x & 63;
    int n = (blockIdx.x * blockDim.x + threadIdx.x) >> 6;
    if (n >= N_NODES) return;
    int o0 = off[n], o1 = off[n + 1];
    float ad_n = adv[n];
    int half = lane >> 5;        // which edge of a pair this half-wave handles
    int qc = lane & 31;          // half4 index within the 128-ch fp16 row
    const half4* hp = (const half4*)h16;   // row = 32 half4
    float m = -INFINITY, den = 0.f;
    float4 acc = make_float4(0.f, 0.f, 0.f, 0.f);
    for (int base = o0; base < o1; base += 64) {
        int j = base + lane;
        bool valid = j < o1;
        int s = valid ? csr[j] : 0;
        float e = valid ? leaky(asv[s] + ad_n) : -INFINITY;
        float cm = e;
#pragma unroll
        for (int k = 32; k; k >>= 1) cm = fmaxf(cm, __shfl_xor(cm, k));
        float nm = fmaxf(m, cm);
        float rs = __expf(m - nm);  // m==-inf first batch -> 0, acc already 0
        den *= rs; acc.x *= rs; acc.y *= rs; acc.z *= rs; acc.w *= rs;
        float w = valid ? __expf(e - nm) : 0.f;
        float ws = w;
#pragma unroll
        for (int k = 32; k; k >>= 1) ws += __shfl_xor(ws, k);
        den += ws;
        m = nm;
        int cnt = min(64, o1 - base);
        int t = 0;
        for (; t + 8 <= cnt; t += 8) {  // 8 edges per iter: 4 rows in flight per lane
            int e0 = t + half, e1 = t + 2 + half, e2 = t + 4 + half, e3 = t + 6 + half;
            int s0 = __shfl(s, e0), s1 = __shfl(s, e1), s2 = __shfl(s, e2), s3 = __shfl(s, e3);
            float w0 = __shfl(w, e0), w1 = __shfl(w, e1), w2 = __shfl(w, e2), w3 = __shfl(w, e3);
            half4 v0 = hp[(size_t)s0 * 32 + qc];
            half4 v1 = hp[(size_t)s1 * 32 + qc];
            half4 v2 = hp[(size_t)s2 * 32 + qc];
            half4 v3 = hp[(size_t)s3 * 32 + qc];
            acc.x = fmaf(w0, (float)v0.x, acc.x); acc.y = fmaf(w0, (float)v0.y, acc.y);
            acc.z = fmaf(w0, (float)v0.z, acc.z); acc.w = fmaf(w0, (float)v0.w, acc.w);
            acc.x = fmaf(w1, (float)v1.x, acc.x); acc.y = fmaf(w1, (float)v1.y, acc.y);
            acc.z = fmaf(w1, (float)v1.z, acc.z); acc.w = fmaf(w1, (float)v1.w, acc.w);
            acc.x = fmaf(w2, (float)v2.x, acc.x); acc.y = fmaf(w2, (float)v2.y, acc.y);
            acc.z = fmaf(w2, (float)v2.z, acc.z); acc.w = fmaf(w2, (float)v2.w, acc.w);
            acc.x = fmaf(w3, (float)v3.x, acc.x); acc.y = fmaf(w3, (float)v3.y, acc.y);
            acc.z = fmaf(w3, (float)v3.z, acc.z); acc.w = fmaf(w3, (float)v3.w, acc.w);
        }
        for (; t + 2 <= cnt; t += 2) {  // pair: each half-wave one edge
            int e0 = t + half;
            int s0 = __shfl(s, e0);
            float w0 = __shfl(w, e0);
            half4 v0 = hp[(size_t)s0 * 32 + qc];
            acc.x = fmaf(w0, (float)v0.x, acc.x); acc.y = fmaf(w0, (float)v0.y, acc.y);
            acc.z = fmaf(w0, (float)v0.z, acc.z); acc.w = fmaf(w0, (float)v0.w, acc.w);
        }
        if (t < cnt) {  // single trailing edge: half 0 only
            int s0 = __shfl(s, t);
            float w0 = __shfl(w, t);
            if (half == 0) {
                half4 v0 = hp[(size_t)s0 * 32 + qc];
                acc.x = fmaf(w0, (float)v0.x, acc.x); acc.y = fmaf(w0, (float)v0.y, acc.y);
                acc.z = fmaf(w0, (float)v0.z, acc.z); acc.w = fmaf(w0, (float)v0.w, acc.w);
            }
        }
    }
    acc.x += __shfl_xor(acc.x, 32); acc.y += __shfl_xor(acc.y, 32);
    acc.z += __shfl_xor(acc.z, 32); acc.w += __shfl_xor(acc.w, 32);
    if (half == 0) {
        float inv = 1.f / den;  // deg >= 1 always (self-loop)
        float4 bv = ((const float4*)bias)[qc];
        float4 o;
        o.x = fmaxf(fmaf(acc.x, inv, bv.x), 0.f);
        o.y = fmaxf(fmaf(acc.y, inv, bv.y), 0.f);
        o.z = fmaxf(fmaf(acc.z, inv, bv.z), 0.f);
        o.w = fmaxf(fmaf(acc.w, inv, bv.w), 0.f);
        ((float4*)outp)[(size_t)n * 32 + qc] = o;
    }
}

// C=16 variant: 8 lane-groups x 8 lanes; each group owns every 8th edge
// (8 rows in flight per wave), cross-group shfl_xor reduce at the end. f32 rows.
__global__ __launch_bounds__(256) void agg16_kernel(
    const float* __restrict__ h, const int* __restrict__ off, const int* __restrict__ csr,
    const float* __restrict__ asv, const float* __restrict__ adv,
    const float* __restrict__ bias, float* __restrict__ outp) {
    int lane = threadIdx.x & 63;
    int n = (blockIdx.x * blockDim.x + threadIdx.x) >> 6;
    if (n >= N_NODES) return;
    int o0 = off[n], o1 = off[n + 1];
    float ad_n = adv[n];
    int g = lane >> 3, pr = lane & 7;  // group, pair-channel
    const float2* hp = (const float2*)h;  // row = 8 float2
    float m = -INFINITY, den = 0.f;
    float ax = 0.f, ay = 0.f;
    for (int base = o0; base < o1; base += 64) {
        int j = base + lane;
        bool valid = j < o1;
        int s = valid ? csr[j] : 0;
        float e = valid ? leaky(asv[s] + ad_n) : -INFINITY;
        float cm = e;
#pragma unroll
        for (int k = 32; k; k >>= 1) cm = fmaxf(cm, __shfl_xor(cm, k));
        float nm = fmaxf(m, cm);
        float rs = __expf(m - nm);
        den *= rs; ax *= rs; ay *= rs;
        float w = valid ? __expf(e - nm) : 0.f;
        float ws = w;
#pragma unroll
        for (int k = 32; k; k >>= 1) ws += __shfl_xor(ws, k);
        den += ws;
        m = nm;
        int cnt = min(64, o1 - base);
        for (int t = g; t < cnt; t += 8) {
            int st = __shfl(s, t);
            float wt = __shfl(w, t);
            float2 v = hp[(size_t)st * 8 + pr];
            ax = fmaf(wt, v.x, ax); ay = fmaf(wt, v.y, ay);
        }
    }
    ax += __shfl_xor(ax, 8);  ay += __shfl_xor(ay, 8);
    ax += __shfl_xor(ax, 16); ay += __shfl_xor(ay, 16);
    ax += __shfl_xor(ax, 32); ay += __shfl_xor(ay, 32);
    if (g == 0) {
        float inv = 1.f / den;
        float vx = fmaxf(fmaf(ax, inv, bias[pr * 2]), 0.f);
        float vy = fmaxf(fmaf(ay, inv, bias[pr * 2 + 1]), 0.f);
        ((float2*)outp)[(size_t)n * 8 + pr] = make_float2(vx, vy);
    }
}

// ---------------- global mean pool + sigmoid ----------------

__global__ void pool_partial_kernel(const float* __restrict__ h3, const int* __restrict__ batch,
                                    float* __restrict__ part) {
    __shared__ float sp[NG * 17];
    int tid = threadIdx.x;
    for (int i = tid; i < NG * 17; i += 256) sp[i] = 0.f;
    __syncthreads();
    int n = blockIdx.x * 256 + tid;
    if (n < N_NODES) {
        int g = batch[n];
        const float4* hv = (const float4*)(h3 + (size_t)n * NC);
#pragma unroll
        for (int j = 0; j < 4; ++j) {
            float4 v = hv[j];
            atomicAdd(&sp[g * 17 + j * 4 + 0], v.x);
            atomicAdd(&sp[g * 17 + j * 4 + 1], v.y);
            atomicAdd(&sp[g * 17 + j * 4 + 2], v.z);
            atomicAdd(&sp[g * 17 + j * 4 + 3], v.w);
        }
        atomicAdd(&sp[g * 17 + 16], 1.f);
    }
    __syncthreads();
    for (int i = tid; i < NG * 17; i += 256) part[(size_t)blockIdx.x * (NG * 17) + i] = sp[i];
}

__global__ void pool_final_kernel(const float* __restrict__ part, float* __restrict__ outp) {
    int tid = threadIdx.x;  // 1024 = 64 graphs x 16 classes
    int g = tid >> 4, c = tid & 15;
    float sum = 0.f, cnt = 0.f;
    for (int b = 0; b < NBLK_POOL; ++b) {
        sum += part[(size_t)b * (NG * 17) + g * 17 + c];
        cnt += part[(size_t)b * (NG * 17) + g * 17 + 16];
    }
    float v = sum / fmaxf(cnt, 1.f);
    outp[g * NC + c] = 1.f / (1.f + __expf(-v));
}

// ---------------- launch ----------------

extern "C" void kernel_launch(void* const* d_in, const int* in_sizes, int n_in,
                              void* d_out, int out_size, void* d_ws, size_t ws_size,
                              hipStream_t stream) {
    const float* x   = (const float*)d_in[0];
    const int*   ei  = (const int*)d_in[1];
    // d_in[2] edge_attr: unused by reference
    const int*   bat = (const int*)d_in[3];
    const float* W1  = (const float*)d_in[4];
    const float* as1 = (const float*)d_in[5];
    const float* ad1 = (const float*)d_in[6];
    const float* b1  = (const float*)d_in[7];
    const float* W2  = (const float*)d_in[8];
    const float* as2 = (const float*)d_in[9];
    const float* ad2 = (const float*)d_in[10];
    const float* b2  = (const float*)d_in[11];
    const float* W3  = (const float*)d_in[12];
    const float* as3 = (const float*)d_in[13];
    const float* ad3 = (const float*)d_in[14];
    const float* b3  = (const float*)d_in[15];
    float* outp = (float*)d_out;

    char* p = (char*)d_ws;
    auto carve = [&](size_t bytes) {
        char* r = p;
        p += (bytes + 255) & ~(size_t)255;
        return r;
    };
    int*    off    = (int*)carve((size_t)(N_NODES + 1) * 4);
    int*    csr    = (int*)carve((size_t)E_TOT * 4);
    int*    gcount = (int*)carve((size_t)NB * 4);
    int*    bOff   = (int*)carve((size_t)(NB + 1) * 4);
    int*    gcur   = (int*)carve((size_t)NB * 4);
    float*  hA     = (float*)carve((size_t)N_NODES * HID * 4);
    float*  hB     = (float*)carve((size_t)N_NODES * HID * 4);
    half_t* h16    = (half_t*)carve((size_t)N_NODES * HID * 2);
    float*  asv    = (float*)carve((size_t)N_NODES * 4);
    float*  adv    = (float*)carve((size_t)N_NODES * 4);
    float*  part   = (float*)carve((size_t)NBLK_POOL * NG * 17 * 4);
    // pairs (6.8MB) aliases hB (25.6MB): last read of pairs is csr_finalize,
    // which completes (stream-ordered) before agg128-L1 first writes hB.
    uint2* pairs  = (uint2*)hB;

    // CSR build (bucketed)
    zero_nb_kernel<<<1, 1024, 0, stream>>>(gcount);
    bucket_hist_kernel<<<(N_EDGES + 4095) / 4096, 256, 0, stream>>>(ei, gcount);
    scanB_kernel<<<1, 1024, 0, stream>>>(gcount, bOff, gcur);
    bucket_scatter_kernel<<<(E_TOT + 4095) / 4096, 256, 0, stream>>>(ei, gcur, pairs);
    csr_finalize_kernel<<<NB, 256, 0, stream>>>(pairs, bOff, off, csr);

    // Layer 1: 11 -> 128
    gemm1_kernel<<<N_NODES, 128, 0, stream>>>(x, W1, hA, h16);
    alpha_kernel<HID><<<(N_NODES + 3) / 4, 256, 0, stream>>>(hA, as1, ad1, asv, adv);
    agg128_kernel<<<(N_NODES + 3) / 4, 256, 0, stream>>>(h16, off, csr, asv, adv, b1, hB);

    // Layer 2: 128 -> 128
    gemm2_kernel<<<(N_NODES + 15) / 16, 256, 0, stream>>>(hB, W2, hA, h16);
    alpha_kernel<HID><<<(N_NODES + 3) / 4, 256, 0, stream>>>(hA, as2, ad2, asv, adv);
    agg128_kernel<<<(N_NODES + 3) / 4, 256, 0, stream>>>(h16, off, csr, asv, adv, b2, hB);

    // Layer 3: 128 -> 16
    gemm3_kernel<<<(N_NODES + 15) / 16, 256, 0, stream>>>(hB, W3, hA);  // hA reused as [N,16]
    alpha_kernel<NC><<<(N_NODES + 3) / 4, 256, 0, stream>>>(hA, as3, ad3, asv, adv);
    agg16_kernel<<<(N_NODES + 3) / 4, 256, 0, stream>>>(hA, off, csr, asv, adv, b3, hB);

    // Pool + sigmoid
    pool_partial_kernel<<<NBLK_POOL, 256, 0, stream>>>(hB, bat, part);
    pool_final_kernel<<<1, 1024, 0, stream>>>(part, outp);
}

// Round 6
// 342.952 us; speedup vs baseline: 1.5723x; 1.1477x over previous
//
#include <hip/hip_runtime.h>
#include <hip/hip_bf16.h>
#include <hip/hip_fp16.h>
#include <math.h>

#define N_NODES 50000
#define N_EDGES 800000
#define F_IN    11
#define HID     128
#define NC      16
#define NG      64
#define E_TOT   (N_EDGES + N_NODES)   // 850000 edges incl. self-loops
#define NBLK_POOL ((N_NODES + 255) / 256)  // 196
#define NEG_SLOPE 0.2f

#define NB   ((N_NODES + 63) >> 6)    // 782 buckets of 64 dst each
#define BCAP 4096                      // LDS pair-staging capacity in csr_finalize

typedef _Float16 half_t;
typedef __attribute__((ext_vector_type(4))) _Float16 half4;
typedef __attribute__((ext_vector_type(8))) _Float16 half8;
typedef __attribute__((ext_vector_type(4))) float f32x4;

__device__ __forceinline__ float leaky(float x) { return x >= 0.f ? x : NEG_SLOPE * x; }

// ---------------- bucketed CSR build (dst-sorted, coalesced writes) ----------------

__global__ void zero_nb_kernel(int* __restrict__ gcount) {
    int i = threadIdx.x;
    if (i < NB) gcount[i] = 0;
}

__global__ __launch_bounds__(256) void bucket_hist_kernel(const int* __restrict__ ei,
                                                          int* __restrict__ gcount) {
    __shared__ int cnt[NB];
    int tid = threadIdx.x;
    for (int i = tid; i < NB; i += 256) cnt[i] = 0;
    __syncthreads();
    int e0 = blockIdx.x * 4096 + tid;
#pragma unroll
    for (int k = 0; k < 16; ++k) {
        int e = e0 + k * 256;
        if (e < N_EDGES) atomicAdd(&cnt[ei[N_EDGES + e] >> 6], 1);
    }
    __syncthreads();
    for (int i = tid; i < NB; i += 256)
        if (cnt[i]) atomicAdd(&gcount[i], cnt[i]);
}

__global__ void scanB_kernel(const int* __restrict__ gcount, int* __restrict__ bOff,
                             int* __restrict__ gcur) {
    __shared__ int ls[1024];
    int tid = threadIdx.x;
    int v = 0;
    if (tid < NB) {
        int sl = N_NODES - (tid << 6);         // self-loops in this bucket
        sl = sl > 64 ? 64 : sl;
        v = gcount[tid] + sl;
    }
    ls[tid] = v;
    __syncthreads();
    for (int ofs = 1; ofs < 1024; ofs <<= 1) {
        int x = (tid >= ofs) ? ls[tid - ofs] : 0;
        __syncthreads();
        ls[tid] += x;
        __syncthreads();
    }
    int excl = (tid > 0) ? ls[tid - 1] : 0;
    if (tid < NB) { bOff[tid] = excl; gcur[tid] = excl; }
    if (tid == 0) bOff[NB] = E_TOT;
}

__global__ __launch_bounds__(256) void bucket_scatter_kernel(const int* __restrict__ ei,
                                                             int* __restrict__ gcur,
                                                             uint2* __restrict__ pairs) {
    __shared__ int cnt[NB];
    __shared__ int base[NB];
    int tid = threadIdx.x;
    for (int i = tid; i < NB; i += 256) cnt[i] = 0;
    __syncthreads();
    int s[16], d[16];
    int e0 = blockIdx.x * 4096 + tid;
#pragma unroll
    for (int k = 0; k < 16; ++k) {
        int e = e0 + k * 256;
        if (e < N_EDGES) { s[k] = ei[e]; d[k] = ei[N_EDGES + e]; }
        else if (e < E_TOT) { s[k] = d[k] = e - N_EDGES; }   // self-loop
        else d[k] = -1;
        if (d[k] >= 0) atomicAdd(&cnt[d[k] >> 6], 1);
    }
    __syncthreads();
    for (int i = tid; i < NB; i += 256)
        base[i] = cnt[i] ? atomicAdd(&gcur[i], cnt[i]) : 0;
    __syncthreads();
    for (int i = tid; i < NB; i += 256) cnt[i] = 0;
    __syncthreads();
#pragma unroll
    for (int k = 0; k < 16; ++k) {
        if (d[k] >= 0) {
            int b = d[k] >> 6;
            int r = atomicAdd(&cnt[b], 1);
            pairs[base[b] + r] = make_uint2((unsigned)s[k], (unsigned)d[k]);
        }
    }
}

__global__ __launch_bounds__(256) void csr_finalize_kernel(const uint2* __restrict__ pairs,
                                                           const int* __restrict__ bOff,
                                                           int* __restrict__ off,
                                                           int* __restrict__ csr) {
    __shared__ uint2 lp[BCAP];      // 32KB staging
    __shared__ int deg[64], offs[65], cnt[64];
    int b = blockIdx.x, tid = threadIdx.x;
    int d0 = b << 6;
    int nd = N_NODES - d0; nd = nd > 64 ? 64 : nd;
    int lo = bOff[b], hi = bOff[b + 1], n = hi - lo;
    if (tid < 64) { deg[tid] = 0; cnt[tid] = 0; }
    __syncthreads();
    bool staged = (n <= BCAP);
    for (int i = tid; i < n; i += 256) {
        uint2 p = pairs[lo + i];
        if (staged) lp[i] = p;
        atomicAdd(&deg[(int)p.y - d0], 1);
    }
    __syncthreads();
    if (tid == 0) {
        int a = 0;
#pragma unroll
        for (int i = 0; i < 64; ++i) { offs[i] = a; a += deg[i]; }
        offs[64] = a;
    }
    __syncthreads();
    if (tid < nd) off[d0 + tid] = lo + offs[tid];
    if (b == (int)gridDim.x - 1 && tid == 0) off[N_NODES] = E_TOT;
    for (int i = tid; i < n; i += 256) {
        uint2 p = staged ? lp[i] : pairs[lo + i];
        int ld = (int)p.y - d0;
        int r = atomicAdd(&cnt[ld], 1);
        csr[lo + offs[ld] + r] = (int)p.x;   // contiguous ~4-5KB region per block
    }
}

// ---------------- weight prep: W2[k][col] f32 -> W2T[col][k] fp16 ----------------

__global__ void prep_w2t_kernel(const float* __restrict__ W2, half_t* __restrict__ W2T) {
    int id = blockIdx.x * 256 + threadIdx.x;   // id = col*128 + k (write-coalesced)
    if (id < HID * HID) {
        int col = id >> 7, k = id & 127;
        W2T[id] = (half_t)W2[k * HID + col];
    }
}

// ---------------- layer-1 GEMM (K=11, VALU) + fused alpha ----------------
// one row per 128-thread block; writes fp16 h only; asv/adv from f32 acc.

__global__ void gemm1_kernel(const float* __restrict__ x, const float* __restrict__ W,
                             const float* __restrict__ a_s, const float* __restrict__ a_d,
                             half_t* __restrict__ h16,
                             float* __restrict__ asv, float* __restrict__ adv) {
    __shared__ float xr[F_IN];
    __shared__ float red[4];
    int row = blockIdx.x;
    int t = threadIdx.x;
    if (t < F_IN) xr[t] = x[row * F_IN + t];
    __syncthreads();
    float acc = 0.f;
#pragma unroll
    for (int k = 0; k < F_IN; ++k) acc = fmaf(xr[k], W[k * HID + t], acc);
    h16[(size_t)row * HID + t] = (half_t)acc;
    float ps = acc * a_s[t], pd = acc * a_d[t];
#pragma unroll
    for (int m = 32; m; m >>= 1) { ps += __shfl_xor(ps, m); pd += __shfl_xor(pd, m); }
    int lane = t & 63, wid = t >> 6;
    if (lane == 0) { red[wid * 2] = ps; red[wid * 2 + 1] = pd; }
    __syncthreads();
    if (t == 0) { asv[row] = red[0] + red[2]; adv[row] = red[1] + red[3]; }
}

// ---------------- layer-2 GEMM: MFMA fp16, no LDS, fused alpha ----------------
// A[N,128] fp16 x W2T[col][k] fp16 -> h16 out fp16; acc f32.
// Fragment layout (gfx950 16x16x32_f16): A row=lane&15, k=(lane>>4)*8+e;
// B col=lane&15, same k; C/D col=lane&15, row=(lane>>4)*4+reg [m89/m91].

__global__ __launch_bounds__(256) void gemm2_mfma_kernel(
    const half_t* __restrict__ A, const half_t* __restrict__ W2T,
    const float* __restrict__ a_s, const float* __restrict__ a_d,
    half_t* __restrict__ outp, float* __restrict__ asv, float* __restrict__ adv) {
    int wid = threadIdx.x >> 6;
    int lane = threadIdx.x & 63;
    int row0 = blockIdx.x * 64 + wid * 16;   // this wave's 16 output rows
    int rl = lane & 15;                       // A-row / B-col / C-col within tile
    int kg = lane >> 4;                       // k-group (8 f16 each)
    int arow = row0 + rl;
    if (arow >= N_NODES) arow = N_NODES - 1;  // clamp; bad rows masked on write
    const half8* Ap = (const half8*)(A + (size_t)arow * HID);
    half8 afrag[4];
#pragma unroll
    for (int kk = 0; kk < 4; ++kk) afrag[kk] = Ap[kk * 4 + kg];
    float ps[4] = {0.f, 0.f, 0.f, 0.f}, pd[4] = {0.f, 0.f, 0.f, 0.f};
#pragma unroll
    for (int ct = 0; ct < 8; ++ct) {          // 8 col-tiles of 16
        f32x4 acc = {0.f, 0.f, 0.f, 0.f};
        const half8* Bp = (const half8*)(W2T + (size_t)(ct * 16 + rl) * HID);
#pragma unroll
        for (int kk = 0; kk < 4; ++kk)
            acc = __builtin_amdgcn_mfma_f32_16x16x32_f16(afrag[kk], Bp[kk * 4 + kg], acc, 0, 0, 0);
        int col = ct * 16 + rl;
        float as_c = a_s[col], ad_c = a_d[col];
#pragma unroll
        for (int i = 0; i < 4; ++i) {
            int r = row0 + kg * 4 + i;
            ps[i] = fmaf(acc[i], as_c, ps[i]);
            pd[i] = fmaf(acc[i], ad_c, pd[i]);
            if (r < N_NODES) outp[(size_t)r * HID + col] = (half_t)acc[i];
        }
    }
    // row-dot reduce across the 16 cols held per (kg,i): lane bits 0-3
#pragma unroll
    for (int m = 1; m <= 8; m <<= 1) {
#pragma unroll
        for (int i = 0; i < 4; ++i) { ps[i] += __shfl_xor(ps[i], m); pd[i] += __shfl_xor(pd[i], m); }
    }
    if (rl == 0) {
#pragma unroll
        for (int i = 0; i < 4; ++i) {
            int r = row0 + kg * 4 + i;
            if (r < N_NODES) { asv[r] = ps[i]; adv[r] = pd[i]; }
        }
    }
}

// ---------------- layer-3 GEMM (fp16 in, f32 out, VALU) + fused alpha ----------------

__global__ __launch_bounds__(256) void gemm3_kernel(const half_t* __restrict__ A16,
                                                    const float* __restrict__ W,
                                                    const float* __restrict__ a_s,
                                                    const float* __restrict__ a_d,
                                                    float* __restrict__ outp,
                                                    float* __restrict__ asv,
                                                    float* __restrict__ adv) {
    __shared__ float hs[16][HID + 1];  // pad: 16 distinct rows read per k
    int tid = threadIdx.x;
    int row0 = blockIdx.x * 16;
    for (int i = tid; i < 16 * HID; i += 256) {
        int r = i >> 7, c = i & 127;
        int gr = row0 + r;
        hs[r][c] = (gr < N_NODES) ? (float)A16[(size_t)gr * HID + c] : 0.f;
    }
    __syncthreads();
    int col = tid & 15, r = tid >> 4;
    float acc = 0.f;
#pragma unroll 4
    for (int k = 0; k < HID; ++k) acc = fmaf(hs[r][k], W[k * NC + col], acc);
    int gr = row0 + r;
    float ps = acc * a_s[col], pd = acc * a_d[col];
#pragma unroll
    for (int m = 1; m <= 8; m <<= 1) { ps += __shfl_xor(ps, m); pd += __shfl_xor(pd, m); }
    if (gr < N_NODES) {
        outp[(size_t)gr * NC + col] = acc;
        if (col == 0) { asv[gr] = ps; adv[gr] = pd; }
    }
}

// ---------------- fused segment-softmax + weighted aggregation ----------------
// One wave per dst node; fp16 gather rows, f32 accumulate, fp16 output (next
// layer's MFMA/gather input). Half-wave per edge, 4 rows in flight per lane.

__global__ __launch_bounds__(256) void agg128_kernel(
    const half_t* __restrict__ h16, const int* __restrict__ off, const int* __restrict__ csr,
    const float* __restrict__ asv, const float* __restrict__ adv,
    const float* __restrict__ bias, half_t* __restrict__ outp) {
    int lane = threadIdx.x & 63;
    int n = (blockIdx.x * blockDim.x + threadIdx.x) >> 6;
    if (n >= N_NODES) return;
    int o0 = off[n], o1 = off[n + 1];
    float ad_n = adv[n];
    int half = lane >> 5;        // which edge of a pair this half-wave handles
    int qc = lane & 31;          // half4 index within the 128-ch fp16 row
    const half4* hp = (const half4*)h16;   // row = 32 half4
    float m = -INFINITY, den = 0.f;
    float4 acc = make_float4(0.f, 0.f, 0.f, 0.f);
    for (int base = o0; base < o1; base += 64) {
        int j = base + lane;
        bool valid = j < o1;
        int s = valid ? csr[j] : 0;
        float e = valid ? leaky(asv[s] + ad_n) : -INFINITY;
        float cm = e;
#pragma unroll
        for (int k = 32; k; k >>= 1) cm = fmaxf(cm, __shfl_xor(cm, k));
        float nm = fmaxf(m, cm);
        float rs = __expf(m - nm);  // m==-inf first batch -> 0, acc already 0
        den *= rs; acc.x *= rs; acc.y *= rs; acc.z *= rs; acc.w *= rs;
        float w = valid ? __expf(e - nm) : 0.f;
        float ws = w;
#pragma unroll
        for (int k = 32; k; k >>= 1) ws += __shfl_xor(ws, k);
        den += ws;
        m = nm;
        int cnt = min(64, o1 - base);
        int t = 0;
        for (; t + 8 <= cnt; t += 8) {  // 8 edges per iter: 4 rows in flight per lane
            int e0 = t + half, e1 = t + 2 + half, e2 = t + 4 + half, e3 = t + 6 + half;
            int s0 = __shfl(s, e0), s1 = __shfl(s, e1), s2 = __shfl(s, e2), s3 = __shfl(s, e3);
            float w0 = __shfl(w, e0), w1 = __shfl(w, e1), w2 = __shfl(w, e2), w3 = __shfl(w, e3);
            half4 v0 = hp[(size_t)s0 * 32 + qc];
            half4 v1 = hp[(size_t)s1 * 32 + qc];
            half4 v2 = hp[(size_t)s2 * 32 + qc];
            half4 v3 = hp[(size_t)s3 * 32 + qc];
            acc.x = fmaf(w0, (float)v0.x, acc.x); acc.y = fmaf(w0, (float)v0.y, acc.y);
            acc.z = fmaf(w0, (float)v0.z, acc.z); acc.w = fmaf(w0, (float)v0.w, acc.w);
            acc.x = fmaf(w1, (float)v1.x, acc.x); acc.y = fmaf(w1, (float)v1.y, acc.y);
            acc.z = fmaf(w1, (float)v1.z, acc.z); acc.w = fmaf(w1, (float)v1.w, acc.w);
            acc.x = fmaf(w2, (float)v2.x, acc.x); acc.y = fmaf(w2, (float)v2.y, acc.y);
            acc.z = fmaf(w2, (float)v2.z, acc.z); acc.w = fmaf(w2, (float)v2.w, acc.w);
            acc.x = fmaf(w3, (float)v3.x, acc.x); acc.y = fmaf(w3, (float)v3.y, acc.y);
            acc.z = fmaf(w3, (float)v3.z, acc.z); acc.w = fmaf(w3, (float)v3.w, acc.w);
        }
        for (; t + 2 <= cnt; t += 2) {  // pair: each half-wave one edge
            int e0 = t + half;
            int s0 = __shfl(s, e0);
            float w0 = __shfl(w, e0);
            half4 v0 = hp[(size_t)s0 * 32 + qc];
            acc.x = fmaf(w0, (float)v0.x, acc.x); acc.y = fmaf(w0, (float)v0.y, acc.y);
            acc.z = fmaf(w0, (float)v0.z, acc.z); acc.w = fmaf(w0, (float)v0.w, acc.w);
        }
        if (t < cnt) {  // single trailing edge: half 0 only
            int s0 = __shfl(s, t);
            float w0 = __shfl(w, t);
            if (half == 0) {
                half4 v0 = hp[(size_t)s0 * 32 + qc];
                acc.x = fmaf(w0, (float)v0.x, acc.x); acc.y = fmaf(w0, (float)v0.y, acc.y);
                acc.z = fmaf(w0, (float)v0.z, acc.z); acc.w = fmaf(w0, (float)v0.w, acc.w);
            }
        }
    }
    acc.x += __shfl_xor(acc.x, 32); acc.y += __shfl_xor(acc.y, 32);
    acc.z += __shfl_xor(acc.z, 32); acc.w += __shfl_xor(acc.w, 32);
    if (half == 0) {
        float inv = 1.f / den;  // deg >= 1 always (self-loop)
        float4 bv = ((const float4*)bias)[qc];
        half4 o;
        o.x = (half_t)fmaxf(fmaf(acc.x, inv, bv.x), 0.f);
        o.y = (half_t)fmaxf(fmaf(acc.y, inv, bv.y), 0.f);
        o.z = (half_t)fmaxf(fmaf(acc.z, inv, bv.z), 0.f);
        o.w = (half_t)fmaxf(fmaf(acc.w, inv, bv.w), 0.f);
        ((half4*)outp)[(size_t)n * 32 + qc] = o;
    }
}

// C=16 variant: 8 lane-groups x 8 lanes; f32 rows (layer-3 h is f32).
__global__ __launch_bounds__(256) void agg16_kernel(
    const float* __restrict__ h, const int* __restrict__ off, const int* __restrict__ csr,
    const float* __restrict__ asv, const float* __restrict__ adv,
    const float* __restrict__ bias, float* __restrict__ outp) {
    int lane = threadIdx.x & 63;
    int n = (blockIdx.x * blockDim.x + threadIdx.x) >> 6;
    if (n >= N_NODES) return;
    int o0 = off[n], o1 = off[n + 1];
    float ad_n = adv[n];
    int g = lane >> 3, pr = lane & 7;  // group, pair-channel
    const float2* hp = (const float2*)h;  // row = 8 float2
    float m = -INFINITY, den = 0.f;
    float ax = 0.f, ay = 0.f;
    for (int base = o0; base < o1; base += 64) {
        int j = base + lane;
        bool valid = j < o1;
        int s = valid ? csr[j] : 0;
        float e = valid ? leaky(asv[s] + ad_n) : -INFINITY;
        float cm = e;
#pragma unroll
        for (int k = 32; k; k >>= 1) cm = fmaxf(cm, __shfl_xor(cm, k));
        float nm = fmaxf(m, cm);
        float rs = __expf(m - nm);
        den *= rs; ax *= rs; ay *= rs;
        float w = valid ? __expf(e - nm) : 0.f;
        float ws = w;
#pragma unroll
        for (int k = 32; k; k >>= 1) ws += __shfl_xor(ws, k);
        den += ws;
        m = nm;
        int cnt = min(64, o1 - base);
        for (int t = g; t < cnt; t += 8) {
            int st = __shfl(s, t);
            float wt = __shfl(w, t);
            float2 v = hp[(size_t)st * 8 + pr];
            ax = fmaf(wt, v.x, ax); ay = fmaf(wt, v.y, ay);
        }
    }
    ax += __shfl_xor(ax, 8);  ay += __shfl_xor(ay, 8);
    ax += __shfl_xor(ax, 16); ay += __shfl_xor(ay, 16);
    ax += __shfl_xor(ax, 32); ay += __shfl_xor(ay, 32);
    if (g == 0) {
        float inv = 1.f / den;
        float vx = fmaxf(fmaf(ax, inv, bias[pr * 2]), 0.f);
        float vy = fmaxf(fmaf(ay, inv, bias[pr * 2 + 1]), 0.f);
        ((float2*)outp)[(size_t)n * 8 + pr] = make_float2(vx, vy);
    }
}

// ---------------- global mean pool + sigmoid ----------------

__global__ void pool_partial_kernel(const float* __restrict__ h3, const int* __restrict__ batch,
                                    float* __restrict__ part) {
    __shared__ float sp[NG * 17];
    int tid = threadIdx.x;
    for (int i = tid; i < NG * 17; i += 256) sp[i] = 0.f;
    __syncthreads();
    int n = blockIdx.x * 256 + tid;
    if (n < N_NODES) {
        int g = batch[n];
        const float4* hv = (const float4*)(h3 + (size_t)n * NC);
#pragma unroll
        for (int j = 0; j < 4; ++j) {
            float4 v = hv[j];
            atomicAdd(&sp[g * 17 + j * 4 + 0], v.x);
            atomicAdd(&sp[g * 17 + j * 4 + 1], v.y);
            atomicAdd(&sp[g * 17 + j * 4 + 2], v.z);
            atomicAdd(&sp[g * 17 + j * 4 + 3], v.w);
        }
        atomicAdd(&sp[g * 17 + 16], 1.f);
    }
    __syncthreads();
    for (int i = tid; i < NG * 17; i += 256) part[(size_t)blockIdx.x * (NG * 17) + i] = sp[i];
}

__global__ void pool_final_kernel(const float* __restrict__ part, float* __restrict__ outp) {
    int tid = threadIdx.x;  // 1024 = 64 graphs x 16 classes
    int g = tid >> 4, c = tid & 15;
    float sum = 0.f, cnt = 0.f;
    for (int b = 0; b < NBLK_POOL; ++b) {
        sum += part[(size_t)b * (NG * 17) + g * 17 + c];
        cnt += part[(size_t)b * (NG * 17) + g * 17 + 16];
    }
    float v = sum / fmaxf(cnt, 1.f);
    outp[g * NC + c] = 1.f / (1.f + __expf(-v));
}

// ---------------- launch ----------------

extern "C" void kernel_launch(void* const* d_in, const int* in_sizes, int n_in,
                              void* d_out, int out_size, void* d_ws, size_t ws_size,
                              hipStream_t stream) {
    const float* x   = (const float*)d_in[0];
    const int*   ei  = (const int*)d_in[1];
    // d_in[2] edge_attr: unused by reference
    const int*   bat = (const int*)d_in[3];
    const float* W1  = (const float*)d_in[4];
    const float* as1 = (const float*)d_in[5];
    const float* ad1 = (const float*)d_in[6];
    const float* b1  = (const float*)d_in[7];
    const float* W2  = (const float*)d_in[8];
    const float* as2 = (const float*)d_in[9];
    const float* ad2 = (const float*)d_in[10];
    const float* b2  = (const float*)d_in[11];
    const float* W3  = (const float*)d_in[12];
    const float* as3 = (const float*)d_in[13];
    const float* ad3 = (const float*)d_in[14];
    const float* b3  = (const float*)d_in[15];
    float* outp = (float*)d_out;

    char* p = (char*)d_ws;
    auto carve = [&](size_t bytes) {
        char* r = p;
        p += (bytes + 255) & ~(size_t)255;
        return r;
    };
    int*    off    = (int*)carve((size_t)(N_NODES + 1) * 4);
    int*    csr    = (int*)carve((size_t)E_TOT * 4);
    int*    gcount = (int*)carve((size_t)NB * 4);
    int*    bOff   = (int*)carve((size_t)(NB + 1) * 4);
    int*    gcur   = (int*)carve((size_t)NB * 4);
    uint2*  pairs  = (uint2*)carve((size_t)E_TOT * 8);
    half_t* h16    = (half_t*)carve((size_t)N_NODES * HID * 2);   // gemm out (L1/L2)
    half_t* o16    = (half_t*)carve((size_t)N_NODES * HID * 2);   // agg out (L1/L2)
    half_t* W2T    = (half_t*)carve((size_t)HID * HID * 2);
    float*  h3     = (float*)carve((size_t)N_NODES * NC * 4);
    float*  o3     = (float*)carve((size_t)N_NODES * NC * 4);
    float*  asv    = (float*)carve((size_t)N_NODES * 4);
    float*  adv    = (float*)carve((size_t)N_NODES * 4);
    float*  part   = (float*)carve((size_t)NBLK_POOL * NG * 17 * 4);

    // CSR build (bucketed)
    zero_nb_kernel<<<1, 1024, 0, stream>>>(gcount);
    bucket_hist_kernel<<<(N_EDGES + 4095) / 4096, 256, 0, stream>>>(ei, gcount);
    scanB_kernel<<<1, 1024, 0, stream>>>(gcount, bOff, gcur);
    bucket_scatter_kernel<<<(E_TOT + 4095) / 4096, 256, 0, stream>>>(ei, gcur, pairs);
    csr_finalize_kernel<<<NB, 256, 0, stream>>>(pairs, bOff, off, csr);

    // weight prep (overlappable with CSR build in graph order; stream-serial is fine)
    prep_w2t_kernel<<<(HID * HID + 255) / 256, 256, 0, stream>>>(W2, W2T);

    // Layer 1: 11 -> 128 (VALU GEMM + fused alpha)
    gemm1_kernel<<<N_NODES, 128, 0, stream>>>(x, W1, as1, ad1, h16, asv, adv);
    agg128_kernel<<<(N_NODES + 3) / 4, 256, 0, stream>>>(h16, off, csr, asv, adv, b1, o16);

    // Layer 2: 128 -> 128 (MFMA fp16 + fused alpha)
    gemm2_mfma_kernel<<<(N_NODES + 63) / 64, 256, 0, stream>>>(o16, W2T, as2, ad2, h16, asv, adv);
    agg128_kernel<<<(N_NODES + 3) / 4, 256, 0, stream>>>(h16, off, csr, asv, adv, b2, o16);

    // Layer 3: 128 -> 16 (VALU GEMM, fp16 in + fused alpha)
    gemm3_kernel<<<(N_NODES + 15) / 16, 256, 0, stream>>>(o16, W3, as3, ad3, h3, asv, adv);
    agg16_kernel<<<(N_NODES + 3) / 4, 256, 0, stream>>>(h3, off, csr, asv, adv, b3, o3);

    // Pool + sigmoid
    pool_partial_kernel<<<NBLK_POOL, 256, 0, stream>>>(o3, bat, part);
    pool_final_kernel<<<1, 1024, 0, stream>>>(part, outp);
}

// Round 7
// 340.739 us; speedup vs baseline: 1.5825x; 1.0065x over previous
//
#include <hip/hip_runtime.h>
#include <hip/hip_bf16.h>
#include <hip/hip_fp16.h>
#include <math.h>

#define N_NODES 50000
#define N_EDGES 800000
#define F_IN    11
#define HID     128
#define NC      16
#define NG      64
#define E_TOT   (N_EDGES + N_NODES)   // 850000 edges incl. self-loops
#define NBLK_POOL ((N_NODES + 255) / 256)  // 196
#define NEG_SLOPE 0.2f

#define NB   ((N_NODES + 63) >> 6)    // 782 buckets of 64 dst each
#define BCAP 4096                      // LDS pair-staging capacity in csr_finalize
#define NHB  ((N_EDGES + 4095) / 4096) // hist blocks (196)

typedef _Float16 half_t;
typedef __attribute__((ext_vector_type(2))) _Float16 half2v;
typedef __attribute__((ext_vector_type(4))) _Float16 half4;
typedef __attribute__((ext_vector_type(8))) _Float16 half8;
typedef __attribute__((ext_vector_type(4))) float f32x4;

__device__ __forceinline__ float leaky(float x) { return x >= 0.f ? x : NEG_SLOPE * x; }

// ---------------- bucketed CSR build (dst-sorted, coalesced writes) ----------------
// pairs packed: bits 0-15 = src (<50000 fits 16b), bits 16-21 = dst&63.

// hist blocks count regular edges per bucket; trailing 64 blocks transpose W2->fp16 W2T.
__global__ __launch_bounds__(256) void bucket_hist_w2t_kernel(const int* __restrict__ ei,
                                                              int* __restrict__ gcount,
                                                              const float* __restrict__ W2,
                                                              half_t* __restrict__ W2T) {
    int tid = threadIdx.x;
    if (blockIdx.x >= NHB) {   // W2T prep: id = col*128 + k (write-coalesced)
        int id = (blockIdx.x - NHB) * 256 + tid;
        if (id < HID * HID) {
            int col = id >> 7, k = id & 127;
            W2T[id] = (half_t)W2[k * HID + col];
        }
        return;
    }
    __shared__ int cnt[NB];
    for (int i = tid; i < NB; i += 256) cnt[i] = 0;
    __syncthreads();
    int e0 = blockIdx.x * 4096 + tid;
#pragma unroll
    for (int k = 0; k < 16; ++k) {
        int e = e0 + k * 256;
        if (e < N_EDGES) atomicAdd(&cnt[ei[N_EDGES + e] >> 6], 1);
    }
    __syncthreads();
    for (int i = tid; i < NB; i += 256)
        if (cnt[i]) atomicAdd(&gcount[i], cnt[i]);
}

__global__ void scanB_kernel(const int* __restrict__ gcount, int* __restrict__ bOff,
                             int* __restrict__ gcur) {
    __shared__ int ls[1024];
    int tid = threadIdx.x;
    int v = 0;
    if (tid < NB) {
        int sl = N_NODES - (tid << 6);         // self-loops in this bucket
        sl = sl > 64 ? 64 : sl;
        v = gcount[tid] + sl;
    }
    ls[tid] = v;
    __syncthreads();
    for (int ofs = 1; ofs < 1024; ofs <<= 1) {
        int x = (tid >= ofs) ? ls[tid - ofs] : 0;
        __syncthreads();
        ls[tid] += x;
        __syncthreads();
    }
    int excl = (tid > 0) ? ls[tid - 1] : 0;
    if (tid < NB) { bOff[tid] = excl; gcur[tid] = excl; }
    if (tid == 0) bOff[NB] = E_TOT;
}

__global__ __launch_bounds__(256) void bucket_scatter_kernel(const int* __restrict__ ei,
                                                             int* __restrict__ gcur,
                                                             unsigned* __restrict__ pairs) {
    __shared__ int cnt[NB];
    __shared__ int base[NB];
    int tid = threadIdx.x;
    for (int i = tid; i < NB; i += 256) cnt[i] = 0;
    __syncthreads();
    int s[16], d[16];
    int e0 = blockIdx.x * 4096 + tid;
#pragma unroll
    for (int k = 0; k < 16; ++k) {
        int e = e0 + k * 256;
        if (e < N_EDGES) { s[k] = ei[e]; d[k] = ei[N_EDGES + e]; }
        else if (e < E_TOT) { s[k] = d[k] = e - N_EDGES; }   // self-loop
        else d[k] = -1;
        if (d[k] >= 0) atomicAdd(&cnt[d[k] >> 6], 1);
    }
    __syncthreads();
    for (int i = tid; i < NB; i += 256)
        base[i] = cnt[i] ? atomicAdd(&gcur[i], cnt[i]) : 0;
    __syncthreads();
    for (int i = tid; i < NB; i += 256) cnt[i] = 0;
    __syncthreads();
#pragma unroll
    for (int k = 0; k < 16; ++k) {
        if (d[k] >= 0) {
            int b = d[k] >> 6;
            int r = atomicAdd(&cnt[b], 1);
            pairs[base[b] + r] = (unsigned)s[k] | ((unsigned)(d[k] & 63) << 16);
        }
    }
}

__global__ __launch_bounds__(256) void csr_finalize_kernel(const unsigned* __restrict__ pairs,
                                                           const int* __restrict__ bOff,
                                                           int* __restrict__ off,
                                                           int* __restrict__ csr) {
    __shared__ unsigned lp[BCAP];      // 16KB staging
    __shared__ int deg[64], offs[65], cnt[64];
    int b = blockIdx.x, tid = threadIdx.x;
    int d0 = b << 6;
    int nd = N_NODES - d0; nd = nd > 64 ? 64 : nd;
    int lo = bOff[b], hi = bOff[b + 1], n = hi - lo;
    if (tid < 64) { deg[tid] = 0; cnt[tid] = 0; }
    __syncthreads();
    bool staged = (n <= BCAP);
    for (int i = tid; i < n; i += 256) {
        unsigned p = pairs[lo + i];
        if (staged) lp[i] = p;
        atomicAdd(&deg[p >> 16], 1);
    }
    __syncthreads();
    if (tid == 0) {
        int a = 0;
#pragma unroll
        for (int i = 0; i < 64; ++i) { offs[i] = a; a += deg[i]; }
        offs[64] = a;
    }
    __syncthreads();
    if (tid < nd) off[d0 + tid] = lo + offs[tid];
    if (b == (int)gridDim.x - 1 && tid == 0) off[N_NODES] = E_TOT;
    for (int i = tid; i < n; i += 256) {
        unsigned p = staged ? lp[i] : pairs[lo + i];
        int ld = p >> 16;
        int r = atomicAdd(&cnt[ld], 1);
        csr[lo + offs[ld] + r] = (int)(p & 0xFFFF);   // contiguous region per block
    }
}

// ---------------- layer-1 GEMM (K=11, VALU) + fused alpha ----------------

__global__ void gemm1_kernel(const float* __restrict__ x, const float* __restrict__ W,
                             const float* __restrict__ a_s, const float* __restrict__ a_d,
                             half_t* __restrict__ h16,
                             float* __restrict__ asv, float* __restrict__ adv) {
    __shared__ float xr[F_IN];
    __shared__ float red[4];
    int row = blockIdx.x;
    int t = threadIdx.x;
    if (t < F_IN) xr[t] = x[row * F_IN + t];
    __syncthreads();
    float acc = 0.f;
#pragma unroll
    for (int k = 0; k < F_IN; ++k) acc = fmaf(xr[k], W[k * HID + t], acc);
    h16[(size_t)row * HID + t] = (half_t)acc;
    float ps = acc * a_s[t], pd = acc * a_d[t];
#pragma unroll
    for (int m = 32; m; m >>= 1) { ps += __shfl_xor(ps, m); pd += __shfl_xor(pd, m); }
    int lane = t & 63, wid = t >> 6;
    if (lane == 0) { red[wid * 2] = ps; red[wid * 2 + 1] = pd; }
    __syncthreads();
    if (t == 0) { asv[row] = red[0] + red[2]; adv[row] = red[1] + red[3]; }
}

// ---------------- layer-2 GEMM: MFMA fp16, no LDS, fused alpha ----------------

__global__ __launch_bounds__(256) void gemm2_mfma_kernel(
    const half_t* __restrict__ A, const half_t* __restrict__ W2T,
    const float* __restrict__ a_s, const float* __restrict__ a_d,
    half_t* __restrict__ outp, float* __restrict__ asv, float* __restrict__ adv) {
    int wid = threadIdx.x >> 6;
    int lane = threadIdx.x & 63;
    int row0 = blockIdx.x * 64 + wid * 16;   // this wave's 16 output rows
    int rl = lane & 15;                       // A-row / B-col / C-col within tile
    int kg = lane >> 4;                       // k-group (8 f16 each)
    int arow = row0 + rl;
    if (arow >= N_NODES) arow = N_NODES - 1;  // clamp; bad rows masked on write
    const half8* Ap = (const half8*)(A + (size_t)arow * HID);
    half8 afrag[4];
#pragma unroll
    for (int kk = 0; kk < 4; ++kk) afrag[kk] = Ap[kk * 4 + kg];
    float ps[4] = {0.f, 0.f, 0.f, 0.f}, pd[4] = {0.f, 0.f, 0.f, 0.f};
#pragma unroll
    for (int ct = 0; ct < 8; ++ct) {          // 8 col-tiles of 16
        f32x4 acc = {0.f, 0.f, 0.f, 0.f};
        const half8* Bp = (const half8*)(W2T + (size_t)(ct * 16 + rl) * HID);
#pragma unroll
        for (int kk = 0; kk < 4; ++kk)
            acc = __builtin_amdgcn_mfma_f32_16x16x32_f16(afrag[kk], Bp[kk * 4 + kg], acc, 0, 0, 0);
        int col = ct * 16 + rl;
        float as_c = a_s[col], ad_c = a_d[col];
#pragma unroll
        for (int i = 0; i < 4; ++i) {
            int r = row0 + kg * 4 + i;
            ps[i] = fmaf(acc[i], as_c, ps[i]);
            pd[i] = fmaf(acc[i], ad_c, pd[i]);
            if (r < N_NODES) outp[(size_t)r * HID + col] = (half_t)acc[i];
        }
    }
#pragma unroll
    for (int m = 1; m <= 8; m <<= 1) {
#pragma unroll
        for (int i = 0; i < 4; ++i) { ps[i] += __shfl_xor(ps[i], m); pd[i] += __shfl_xor(pd[i], m); }
    }
    if (rl == 0) {
#pragma unroll
        for (int i = 0; i < 4; ++i) {
            int r = row0 + kg * 4 + i;
            if (r < N_NODES) { asv[r] = ps[i]; adv[r] = pd[i]; }
        }
    }
}

// ---------------- layer-3 GEMM (fp16 in, fp16 out, VALU) + fused alpha ----------------

__global__ __launch_bounds__(256) void gemm3_kernel(const half_t* __restrict__ A16,
                                                    const float* __restrict__ W,
                                                    const float* __restrict__ a_s,
                                                    const float* __restrict__ a_d,
                                                    half_t* __restrict__ outp,
                                                    float* __restrict__ asv,
                                                    float* __restrict__ adv) {
    __shared__ float hs[16][HID + 1];  // pad: 16 distinct rows read per k
    int tid = threadIdx.x;
    int row0 = blockIdx.x * 16;
    for (int i = tid; i < 16 * HID; i += 256) {
        int r = i >> 7, c = i & 127;
        int gr = row0 + r;
        hs[r][c] = (gr < N_NODES) ? (float)A16[(size_t)gr * HID + c] : 0.f;
    }
    __syncthreads();
    int col = tid & 15, r = tid >> 4;
    float acc = 0.f;
#pragma unroll 4
    for (int k = 0; k < HID; ++k) acc = fmaf(hs[r][k], W[k * NC + col], acc);
    int gr = row0 + r;
    float ps = acc * a_s[col], pd = acc * a_d[col];
#pragma unroll
    for (int m = 1; m <= 8; m <<= 1) { ps += __shfl_xor(ps, m); pd += __shfl_xor(pd, m); }
    if (gr < N_NODES) {
        outp[(size_t)gr * NC + col] = (half_t)acc;   // fp16: 1.6MB table, per-XCD L2-resident
        if (col == 0) { asv[gr] = ps; adv[gr] = pd; }
    }
}

// ---------------- fused segment-softmax + weighted aggregation ----------------
// One wave per dst node; fp16 gather rows, f32 accumulate, fp16 output.
// Gather: half-wave per edge, 16 edges/iter -> 8 rows in flight per lane (MLP).

__global__ __launch_bounds__(256) void agg128_kernel(
    const half_t* __restrict__ h16, const int* __restrict__ off, const int* __restrict__ csr,
    const float* __restrict__ asv, const float* __restrict__ adv,
    const float* __restrict__ bias, half_t* __restrict__ outp) {
    int lane = threadIdx.x & 63;
    int n = (blockIdx.x * blockDim.x + threadIdx.x) >> 6;
    if (n >= N_NODES) return;
    int o0 = off[n], o1 = off[n + 1];
    float ad_n = adv[n];
    int half = lane >> 5;        // which edge of a pair this half-wave handles
    int qc = lane & 31;          // half4 index within the 128-ch fp16 row
    const half4* hp = (const half4*)h16;   // row = 32 half4
    float m = -INFINITY, den = 0.f;
    float4 acc = make_float4(0.f, 0.f, 0.f, 0.f);
    for (int base = o0; base < o1; base += 64) {
        int j = base + lane;
        bool valid = j < o1;
        int s = valid ? csr[j] : 0;
        float e = valid ? leaky(asv[s] + ad_n) : -INFINITY;
        float cm = e;
#pragma unroll
        for (int k = 32; k; k >>= 1) cm = fmaxf(cm, __shfl_xor(cm, k));
        float nm = fmaxf(m, cm);
        float rs = __expf(m - nm);  // m==-inf first batch -> 0, acc already 0
        den *= rs; acc.x *= rs; acc.y *= rs; acc.z *= rs; acc.w *= rs;
        float w = valid ? __expf(e - nm) : 0.f;
        float ws = w;
#pragma unroll
        for (int k = 32; k; k >>= 1) ws += __shfl_xor(ws, k);
        den += ws;
        m = nm;
        int cnt = min(64, o1 - base);
        int t = 0;
        for (; t + 16 <= cnt; t += 16) {  // 16 edges: 8 rows in flight per lane
            int sv[8]; float wv[8]; half4 vv[8];
#pragma unroll
            for (int u = 0; u < 8; ++u) {
                sv[u] = __shfl(s, t + 2 * u + half);
                wv[u] = __shfl(w, t + 2 * u + half);
            }
#pragma unroll
            for (int u = 0; u < 8; ++u) vv[u] = hp[(size_t)sv[u] * 32 + qc];
#pragma unroll
            for (int u = 0; u < 8; ++u) {
                acc.x = fmaf(wv[u], (float)vv[u].x, acc.x);
                acc.y = fmaf(wv[u], (float)vv[u].y, acc.y);
                acc.z = fmaf(wv[u], (float)vv[u].z, acc.z);
                acc.w = fmaf(wv[u], (float)vv[u].w, acc.w);
            }
        }
        for (; t + 8 <= cnt; t += 8) {  // 8 edges: 4 rows in flight per lane
            int sv[4]; float wv[4]; half4 vv[4];
#pragma unroll
            for (int u = 0; u < 4; ++u) {
                sv[u] = __shfl(s, t + 2 * u + half);
                wv[u] = __shfl(w, t + 2 * u + half);
            }
#pragma unroll
            for (int u = 0; u < 4; ++u) vv[u] = hp[(size_t)sv[u] * 32 + qc];
#pragma unroll
            for (int u = 0; u < 4; ++u) {
                acc.x = fmaf(wv[u], (float)vv[u].x, acc.x);
                acc.y = fmaf(wv[u], (float)vv[u].y, acc.y);
                acc.z = fmaf(wv[u], (float)vv[u].z, acc.z);
                acc.w = fmaf(wv[u], (float)vv[u].w, acc.w);
            }
        }
        for (; t + 2 <= cnt; t += 2) {  // pair: each half-wave one edge
            int s0 = __shfl(s, t + half);
            float w0 = __shfl(w, t + half);
            half4 v0 = hp[(size_t)s0 * 32 + qc];
            acc.x = fmaf(w0, (float)v0.x, acc.x); acc.y = fmaf(w0, (float)v0.y, acc.y);
            acc.z = fmaf(w0, (float)v0.z, acc.z); acc.w = fmaf(w0, (float)v0.w, acc.w);
        }
        if (t < cnt) {  // single trailing edge: half 0 only
            int s0 = __shfl(s, t);
            float w0 = __shfl(w, t);
            if (half == 0) {
                half4 v0 = hp[(size_t)s0 * 32 + qc];
                acc.x = fmaf(w0, (float)v0.x, acc.x); acc.y = fmaf(w0, (float)v0.y, acc.y);
                acc.z = fmaf(w0, (float)v0.z, acc.z); acc.w = fmaf(w0, (float)v0.w, acc.w);
            }
        }
    }
    acc.x += __shfl_xor(acc.x, 32); acc.y += __shfl_xor(acc.y, 32);
    acc.z += __shfl_xor(acc.z, 32); acc.w += __shfl_xor(acc.w, 32);
    if (half == 0) {
        float inv = 1.f / den;  // deg >= 1 always (self-loop)
        float4 bv = ((const float4*)bias)[qc];
        half4 o;
        o.x = (half_t)fmaxf(fmaf(acc.x, inv, bv.x), 0.f);
        o.y = (half_t)fmaxf(fmaf(acc.y, inv, bv.y), 0.f);
        o.z = (half_t)fmaxf(fmaf(acc.z, inv, bv.z), 0.f);
        o.w = (half_t)fmaxf(fmaf(acc.w, inv, bv.w), 0.f);
        ((half4*)outp)[(size_t)n * 32 + qc] = o;
    }
}

// C=16 variant: 8 lane-groups x 8 lanes; fp16 rows (1.6MB, L2-resident), f32 out.
__global__ __launch_bounds__(256) void agg16_kernel(
    const half_t* __restrict__ h, const int* __restrict__ off, const int* __restrict__ csr,
    const float* __restrict__ asv, const float* __restrict__ adv,
    const float* __restrict__ bias, float* __restrict__ outp) {
    int lane = threadIdx.x & 63;
    int n = (blockIdx.x * blockDim.x + threadIdx.x) >> 6;
    if (n >= N_NODES) return;
    int o0 = off[n], o1 = off[n + 1];
    float ad_n = adv[n];
    int g = lane >> 3, pr = lane & 7;  // group, pair-channel
    const half2v* hp = (const half2v*)h;  // row = 8 half2v (32B)
    float m = -INFINITY, den = 0.f;
    float ax = 0.f, ay = 0.f;
    for (int base = o0; base < o1; base += 64) {
        int j = base + lane;
        bool valid = j < o1;
        int s = valid ? csr[j] : 0;
        float e = valid ? leaky(asv[s] + ad_n) : -INFINITY;
        float cm = e;
#pragma unroll
        for (int k = 32; k; k >>= 1) cm = fmaxf(cm, __shfl_xor(cm, k));
        float nm = fmaxf(m, cm);
        float rs = __expf(m - nm);
        den *= rs; ax *= rs; ay *= rs;
        float w = valid ? __expf(e - nm) : 0.f;
        float ws = w;
#pragma unroll
        for (int k = 32; k; k >>= 1) ws += __shfl_xor(ws, k);
        den += ws;
        m = nm;
        int cnt = min(64, o1 - base);
        for (int t = g; t < cnt; t += 8) {
            int st = __shfl(s, t);
            float wt = __shfl(w, t);
            half2v v = hp[(size_t)st * 8 + pr];
            ax = fmaf(wt, (float)v.x, ax); ay = fmaf(wt, (float)v.y, ay);
        }
    }
    ax += __shfl_xor(ax, 8);  ay += __shfl_xor(ay, 8);
    ax += __shfl_xor(ax, 16); ay += __shfl_xor(ay, 16);
    ax += __shfl_xor(ax, 32); ay += __shfl_xor(ay, 32);
    if (g == 0) {
        float inv = 1.f / den;
        float vx = fmaxf(fmaf(ax, inv, bias[pr * 2]), 0.f);
        float vy = fmaxf(fmaf(ay, inv, bias[pr * 2 + 1]), 0.f);
        ((float2*)outp)[(size_t)n * 8 + pr] = make_float2(vx, vy);
    }
}

// ---------------- global mean pool + sigmoid ----------------

__global__ void pool_partial_kernel(const float* __restrict__ h3, const int* __restrict__ batch,
                                    float* __restrict__ part) {
    __shared__ float sp[NG * 17];
    int tid = threadIdx.x;
    for (int i = tid; i < NG * 17; i += 256) sp[i] = 0.f;
    __syncthreads();
    int n = blockIdx.x * 256 + tid;
    if (n < N_NODES) {
        int g = batch[n];
        const float4* hv = (const float4*)(h3 + (size_t)n * NC);
#pragma unroll
        for (int j = 0; j < 4; ++j) {
            float4 v = hv[j];
            atomicAdd(&sp[g * 17 + j * 4 + 0], v.x);
            atomicAdd(&sp[g * 17 + j * 4 + 1], v.y);
            atomicAdd(&sp[g * 17 + j * 4 + 2], v.z);
            atomicAdd(&sp[g * 17 + j * 4 + 3], v.w);
        }
        atomicAdd(&sp[g * 17 + 16], 1.f);
    }
    __syncthreads();
    for (int i = tid; i < NG * 17; i += 256) part[(size_t)blockIdx.x * (NG * 17) + i] = sp[i];
}

__global__ void pool_final_kernel(const float* __restrict__ part, float* __restrict__ outp) {
    int tid = threadIdx.x;  // 1024 = 64 graphs x 16 classes
    int g = tid >> 4, c = tid & 15;
    float sum = 0.f, cnt = 0.f;
    for (int b = 0; b < NBLK_POOL; ++b) {
        sum += part[(size_t)b * (NG * 17) + g * 17 + c];
        cnt += part[(size_t)b * (NG * 17) + g * 17 + 16];
    }
    float v = sum / fmaxf(cnt, 1.f);
    outp[g * NC + c] = 1.f / (1.f + __expf(-v));
}

// ---------------- launch ----------------

extern "C" void kernel_launch(void* const* d_in, const int* in_sizes, int n_in,
                              void* d_out, int out_size, void* d_ws, size_t ws_size,
                              hipStream_t stream) {
    const float* x   = (const float*)d_in[0];
    const int*   ei  = (const int*)d_in[1];
    // d_in[2] edge_attr: unused by reference
    const int*   bat = (const int*)d_in[3];
    const float* W1  = (const float*)d_in[4];
    const float* as1 = (const float*)d_in[5];
    const float* ad1 = (const float*)d_in[6];
    const float* b1  = (const float*)d_in[7];
    const float* W2  = (const float*)d_in[8];
    const float* as2 = (const float*)d_in[9];
    const float* ad2 = (const float*)d_in[10];
    const float* b2  = (const float*)d_in[11];
    const float* W3  = (const float*)d_in[12];
    const float* as3 = (const float*)d_in[13];
    const float* ad3 = (const float*)d_in[14];
    const float* b3  = (const float*)d_in[15];
    float* outp = (float*)d_out;

    char* p = (char*)d_ws;
    auto carve = [&](size_t bytes) {
        char* r = p;
        p += (bytes + 255) & ~(size_t)255;
        return r;
    };
    int*      off    = (int*)carve((size_t)(N_NODES + 1) * 4);
    int*      csr    = (int*)carve((size_t)E_TOT * 4);
    int*      gcount = (int*)carve((size_t)NB * 4);
    int*      bOff   = (int*)carve((size_t)(NB + 1) * 4);
    int*      gcur   = (int*)carve((size_t)NB * 4);
    unsigned* pairs  = (unsigned*)carve((size_t)E_TOT * 4);
    half_t*   h16    = (half_t*)carve((size_t)N_NODES * HID * 2);   // gemm out
    half_t*   o16    = (half_t*)carve((size_t)N_NODES * HID * 2);   // agg out
    half_t*   W2T    = (half_t*)carve((size_t)HID * HID * 2);
    half_t*   h3     = (half_t*)carve((size_t)N_NODES * NC * 2);
    float*    o3     = (float*)carve((size_t)N_NODES * NC * 4);
    float*    asv    = (float*)carve((size_t)N_NODES * 4);
    float*    adv    = (float*)carve((size_t)N_NODES * 4);
    float*    part   = (float*)carve((size_t)NBLK_POOL * NG * 17 * 4);

    // CSR build (bucketed) + W2T prep folded into hist launch
    hipMemsetAsync(gcount, 0, (size_t)NB * 4, stream);
    bucket_hist_w2t_kernel<<<NHB + 64, 256, 0, stream>>>(ei, gcount, W2, W2T);
    scanB_kernel<<<1, 1024, 0, stream>>>(gcount, bOff, gcur);
    bucket_scatter_kernel<<<(E_TOT + 4095) / 4096, 256, 0, stream>>>(ei, gcur, pairs);
    csr_finalize_kernel<<<NB, 256, 0, stream>>>(pairs, bOff, off, csr);

    // Layer 1: 11 -> 128 (VALU GEMM + fused alpha)
    gemm1_kernel<<<N_NODES, 128, 0, stream>>>(x, W1, as1, ad1, h16, asv, adv);
    agg128_kernel<<<(N_NODES + 3) / 4, 256, 0, stream>>>(h16, off, csr, asv, adv, b1, o16);

    // Layer 2: 128 -> 128 (MFMA fp16 + fused alpha)
    gemm2_mfma_kernel<<<(N_NODES + 63) / 64, 256, 0, stream>>>(o16, W2T, as2, ad2, h16, asv, adv);
    agg128_kernel<<<(N_NODES + 3) / 4, 256, 0, stream>>>(h16, off, csr, asv, adv, b2, o16);

    // Layer 3: 128 -> 16 (VALU GEMM, fp16 in/out + fused alpha)
    gemm3_kernel<<<(N_NODES + 15) / 16, 256, 0, stream>>>(o16, W3, as3, ad3, h3, asv, adv);
    agg16_kernel<<<(N_NODES + 3) / 4, 256, 0, stream>>>(h3, off, csr, asv, adv, b3, o3);

    // Pool + sigmoid
    pool_partial_kernel<<<NBLK_POOL, 256, 0, stream>>>(o3, bat, part);
    pool_final_kernel<<<1, 1024, 0, stream>>>(part, outp);
}